// Round 1
// baseline (1043.758 us; speedup 1.0000x reference)
//
#include <hip/hip_runtime.h>
#include <cstdint>

// ---------------------------------------------------------------------------
// Problem constants
// ---------------------------------------------------------------------------
#define B_    128
#define CIN   1024
#define NPOS  196          // 14*14
#define DM    384
#define NH_   12
#define HD_   32
#define DFF_  1536
#define MT    25088        // B_*NPOS
#define SCALE_Q 0.17677669529663687f   // 1/sqrt(32)

typedef unsigned short u16;
typedef __attribute__((ext_vector_type(8))) short  short8;   // 8 bf16 (4 VGPR)
typedef __attribute__((ext_vector_type(4))) float  f32x4;    // MFMA C/D

__device__ __forceinline__ u16 f2bf(float f) {
  union { float f; uint32_t u; } v; v.f = f;
  uint32_t u = v.u;
  return (u16)((u + 0x7fffu + ((u >> 16) & 1u)) >> 16);
}
__device__ __forceinline__ float bf2f(u16 h) {
  union { uint32_t u; float f; } v; v.u = ((uint32_t)h) << 16;
  return v.f;
}

#define GLDS16(g, l)                                                           \
  __builtin_amdgcn_global_load_lds(                                            \
      (const __attribute__((address_space(1))) void*)(g),                      \
      (__attribute__((address_space(3))) void*)(l), 16, 0, 0)

// ---------------------------------------------------------------------------
// Generic bf16 MFMA GEMM:  out = epi( A[M x K] * W[N x K]^T )
// 128x128 tile, 4 waves (2x2 of 64x64), BK=32, 16 MFMA / K-step.
// LDS tiles stored s-major [4][128][8] so global_load_lds dest is linear and
// ds_read_b128 fragment reads are consecutive-16B-per-lane (conflict-free).
// MODE: 0 = bias+relu6 -> bf16   (fc1, mlp1)
//       1 = bias       -> f32    (fc2)
//       2 = plain      -> bf16   (qkv)
//       3 = bias+res   -> f32    (proj, mlp2)
//       4 = split-K partial -> f32 (lin head)
// ---------------------------------------------------------------------------
template <int MODE>
__global__ __launch_bounds__(256) void gemm_k(
    const u16* __restrict__ A, const u16* __restrict__ W,
    const float* __restrict__ bias, const float* __restrict__ res,
    void* __restrict__ outp,
    int M, int N, int K, int lda, int ldw, int nTN, int splitK)
{
  __shared__ __align__(16) u16 As[4 * 128 * 8];
  __shared__ __align__(16) u16 Bs[4 * 128 * 8];

  int bid = blockIdx.x;
  int split = 0, mT, nT;
  if (MODE == 4) { split = bid / nTN; nT = bid % nTN; mT = 0; }
  else           { mT = bid / nTN;    nT = bid % nTN; }

  const u16* Ab = A + (size_t)split * splitK;
  const u16* Wb = W + (size_t)split * splitK;
  float* outF = (float*)outp + ((MODE == 4) ? (size_t)split * (size_t)M * N : (size_t)0);
  u16*   outU = (u16*)outp;

  int tid = threadIdx.x;
  int wv = tid >> 6, ln = tid & 63;
  int q = ln >> 4, c = ln & 15;
  int wr = wv >> 1, wc = wv & 1;
  int mBase = mT * 128, nBase = nT * 128;

  f32x4 acc[4][4];
#pragma unroll
  for (int i = 0; i < 4; i++)
#pragma unroll
    for (int j = 0; j < 4; j++) acc[i][j] = (f32x4){0.f, 0.f, 0.f, 0.f};

  const u16* Ag = Ab + (size_t)mBase * lda;
  const u16* Wg = Wb + (size_t)nBase * ldw;

  for (int k0 = 0; k0 < K; k0 += 32) {
    // ---- stage 8KB A-tile + 8KB W-tile via global_load_lds (16B/lane) ----
#pragma unroll
    for (int i = 0; i < 2; i++) {
      int ch = wv * 2 + i;             // chunk 0..7 (1024B each)
      int s = ch >> 1;                 // k-slot (8 bf16)
      int r = (ch & 1) * 64 + ln;      // tile row
      GLDS16(Ag + (size_t)r * lda + (k0 + s * 8), &As[ch * 512]);
      GLDS16(Wg + (size_t)r * ldw + (k0 + s * 8), &Bs[ch * 512]);
    }
    __syncthreads();
    short8 afr[4], bfr[4];
#pragma unroll
    for (int mt2 = 0; mt2 < 4; mt2++)
      afr[mt2] = *(const short8*)&As[((q * 128) + wr * 64 + mt2 * 16 + c) * 8];
#pragma unroll
    for (int nt2 = 0; nt2 < 4; nt2++)
      bfr[nt2] = *(const short8*)&Bs[((q * 128) + wc * 64 + nt2 * 16 + c) * 8];
#pragma unroll
    for (int mt2 = 0; mt2 < 4; mt2++)
#pragma unroll
      for (int nt2 = 0; nt2 < 4; nt2++)
        acc[mt2][nt2] = __builtin_amdgcn_mfma_f32_16x16x32_bf16(
            afr[mt2], bfr[nt2], acc[mt2][nt2], 0, 0, 0);
    __syncthreads();
  }

  // ---- epilogue ----
#pragma unroll
  for (int mt2 = 0; mt2 < 4; mt2++) {
    int row0 = mBase + wr * 64 + mt2 * 16 + q * 4;
#pragma unroll
    for (int nt2 = 0; nt2 < 4; nt2++) {
      int col = nBase + wc * 64 + nt2 * 16 + c;
      float bv = (MODE == 0 || MODE == 1 || MODE == 3) ? bias[col] : 0.f;
      f32x4 v = acc[mt2][nt2];
#pragma unroll
      for (int e = 0; e < 4; e++) {
        int row = row0 + e;
        float x = v[e] + bv;
        if (MODE == 0) x = fminf(fmaxf(x, 0.f), 6.f);
        if (MODE == 3) x += res[(size_t)row * N + col];
        if (MODE == 0 || MODE == 2) outU[(size_t)row * N + col] = f2bf(x);
        else                        outF[(size_t)row * N + col] = x;
      }
    }
  }
}

// ---------------------------------------------------------------------------
// x (B, CIN, NPOS) f32  ->  A_t (B*NPOS, CIN) bf16   (tiled transpose + cast)
// ---------------------------------------------------------------------------
__global__ __launch_bounds__(256) void transpose_cast_k(
    const float* __restrict__ x, u16* __restrict__ At)
{
  __shared__ float t[32][33];
  int c0 = blockIdx.x * 32, n0 = blockIdx.y * 32, b = blockIdx.z;
  int tx = threadIdx.x, ty = threadIdx.y;
  const float* xb = x + (size_t)b * CIN * NPOS;
#pragma unroll
  for (int i = 0; i < 4; i++) {
    int cc = c0 + ty + i * 8, nn = n0 + tx;
    t[ty + i * 8][tx] = (nn < NPOS) ? xb[(size_t)cc * NPOS + nn] : 0.f;
  }
  __syncthreads();
  u16* Ab = At + (size_t)b * NPOS * CIN;
#pragma unroll
  for (int i = 0; i < 4; i++) {
    int nn = n0 + ty + i * 8, cc = c0 + tx;
    if (nn < NPOS) Ab[(size_t)nn * CIN + cc] = f2bf(t[tx][ty + i * 8]);
  }
}

// ---------------------------------------------------------------------------
// depthwise 3x3 SAME conv + bias + identity residual (fp32)
// ---------------------------------------------------------------------------
__global__ __launch_bounds__(256) void conv_res_k(
    const float* __restrict__ T0, const float* __restrict__ pcw,
    const float* __restrict__ pcb, float* __restrict__ T1)
{
  int idx = blockIdx.x * 256 + threadIdx.x;
  if (idx >= B_ * NPOS * 96) return;
  int d4 = idx % 96; int rem = idx / 96;
  int n = rem % NPOS; int b = rem / NPOS;
  int hh = n / 14, ww = n % 14;
  int d0 = d4 * 4;
  float w9[4][9];
#pragma unroll
  for (int j = 0; j < 4; j++)
#pragma unroll
    for (int t = 0; t < 9; t++) w9[j][t] = pcw[(d0 + j) * 9 + t];
  const float* base = T0 + (size_t)b * NPOS * DM;
  float4 ctr = *(const float4*)(base + (size_t)n * DM + d0);
  float ax = ctr.x + pcb[d0], ay = ctr.y + pcb[d0 + 1];
  float az = ctr.z + pcb[d0 + 2], aw = ctr.w + pcb[d0 + 3];
#pragma unroll
  for (int kh = 0; kh < 3; kh++) {
    int h2 = hh + kh - 1;
    if (h2 < 0 || h2 >= 14) continue;
#pragma unroll
    for (int kw = 0; kw < 3; kw++) {
      int w2 = ww + kw - 1;
      if (w2 < 0 || w2 >= 14) continue;
      float4 v = *(const float4*)(base + (size_t)(h2 * 14 + w2) * DM + d0);
      int t = kh * 3 + kw;
      ax += v.x * w9[0][t]; ay += v.y * w9[1][t];
      az += v.z * w9[2][t]; aw += v.w * w9[3][t];
    }
  }
  float4 o = {ax, ay, az, aw};
  *(float4*)(T1 + (size_t)b * NPOS * DM + (size_t)n * DM + d0) = o;
}

// ---------------------------------------------------------------------------
// LayerNorm(384) f32 -> bf16, one wave per row
// ---------------------------------------------------------------------------
__global__ __launch_bounds__(256) void ln_k(
    const float* __restrict__ in, const float* __restrict__ w,
    const float* __restrict__ bb, u16* __restrict__ out)
{
  int row = blockIdx.x * 4 + (threadIdx.x >> 6);
  int ln = threadIdx.x & 63;
  const float* r = in + (size_t)row * DM;
  float v[6]; float s = 0.f, sq = 0.f;
#pragma unroll
  for (int j = 0; j < 6; j++) { v[j] = r[ln + 64 * j]; s += v[j]; sq += v[j] * v[j]; }
#pragma unroll
  for (int o = 1; o < 64; o <<= 1) { s += __shfl_xor(s, o, 64); sq += __shfl_xor(sq, o, 64); }
  float mu = s * (1.f / 384.f);
  float var = sq * (1.f / 384.f) - mu * mu;
  float rs = rsqrtf(var + 1e-5f);
  u16* orow = out + (size_t)row * DM;
#pragma unroll
  for (int j = 0; j < 6; j++) { int d = ln + 64 * j; orow[d] = f2bf((v[j] - mu) * rs * w[d] + bb[d]); }
}

// ---------------------------------------------------------------------------
// rpe_scores[b,h,i,t] = SCALE_Q * sum_d q[b,h,i,d] * table[d,t]   (fp32)
// ---------------------------------------------------------------------------
__global__ __launch_bounds__(256) void rpe_k(
    const u16* __restrict__ QKV, const float* __restrict__ tabG,
    float* __restrict__ Rb)
{
  __shared__ float qs[NPOS * 32];
  __shared__ float tab[32 * 49];
  int bh = blockIdx.x; int b = bh / NH_, h = bh % NH_;
  int tid = threadIdx.x;
  size_t qoff = (size_t)b * NPOS * 1152 + h * 32;
  for (int idx = tid; idx < NPOS * 32; idx += 256) {
    int n = idx >> 5, d = idx & 31;
    qs[idx] = bf2f(QKV[qoff + (size_t)n * 1152 + d]);
  }
  for (int idx = tid; idx < 32 * 49; idx += 256) tab[idx] = tabG[idx];
  __syncthreads();
  for (int idx = tid; idx < NPOS * 49; idx += 256) {
    int i = idx / 49, t = idx - i * 49;
    float s = 0.f;
#pragma unroll
    for (int d = 0; d < 32; d++) s += qs[i * 32 + d] * tab[d * 49 + t];
    Rb[(size_t)bh * 9604 + idx] = s * SCALE_Q;
  }
}

// ---------------------------------------------------------------------------
// Fused attention per (b,h): S = Q K^T (MFMA, frags straight from global),
// + analytic relative-position bucket bias, fp32 softmax in registers,
// P (bf16, LDS strip) x V (LDS, transposed) -> AO bf16.
// ---------------------------------------------------------------------------
__global__ __launch_bounds__(256) void attn_k(
    const u16* __restrict__ QKV, const float* __restrict__ Rb,
    u16* __restrict__ AO)
{
  __shared__ __align__(16) u16 Vt[32 * 232];       // V^T [d][j], padded cols
  __shared__ __align__(16) u16 Ps[4][16 * 232];    // per-wave P strip
  int bh = blockIdx.x; int b = bh / NH_, h = bh % NH_;
  int tid = threadIdx.x;
  int wv = tid >> 6, ln = tid & 63;
  int q = ln >> 4, c = ln & 15;
  size_t rowbase = (size_t)b * NPOS * 1152 + h * 32;

  // V -> Vt (transposed), zero pad j in [196,232)
  for (int idx = tid; idx < NPOS * 32; idx += 256) {
    int n = idx >> 5, d = idx & 31;
    Vt[d * 232 + n] = QKV[rowbase + 768 + (size_t)n * 1152 + d];
  }
  for (int idx = tid; idx < 32 * 36; idx += 256) {
    int d = idx / 36, jj = idx - d * 36;
    Vt[d * 232 + 196 + jj] = 0;
  }
  {
    u16* Pw0 = Ps[wv];               // zero P pad cols [208,232)
    for (int idx = ln; idx < 16 * 24; idx += 64) {
      int rr = idx / 24, cc2 = idx - rr * 24;
      Pw0[rr * 232 + 208 + cc2] = 0;
    }
  }
  __syncthreads();

  const float* Rbb = Rb + (size_t)bh * 9604;
  u16* Pw = Ps[wv];

  for (int mt = wv; mt < 13; mt += 4) {
    int mb = mt * 16;
    int irow = mb + c; if (irow > 195) irow = 195;
    short8 afrag = *(const short8*)(QKV + rowbase + (size_t)irow * 1152 + q * 8);

    f32x4 sacc[13];
#pragma unroll
    for (int nt = 0; nt < 13; nt++) {
      int jc = nt * 16 + c; if (jc > 195) jc = 195;
      short8 bfrag = *(const short8*)(QKV + rowbase + 384 + (size_t)jc * 1152 + q * 8);
      f32x4 z = {0.f, 0.f, 0.f, 0.f};
      sacc[nt] = __builtin_amdgcn_mfma_f32_16x16x32_bf16(afrag, bfrag, z, 0, 0, 0);
    }

    // scale + bucket bias + mask
    int i0 = mb + q * 4;
#pragma unroll
    for (int nt = 0; nt < 13; nt++) {
#pragma unroll
      for (int e = 0; e < 4; e++) {
        int i = i0 + e; int j = nt * 16 + c;
        float sv;
        if (i < 196 && j < 196) {
          int ri = i / 14, ci = i - ri * 14;
          int rj = j / 14, cj = j - rj * 14;
          int dr = ri - rj, dc = ci - cj;
          int adr = dr < 0 ? -dr : dr, adc = dc < 0 ? -dc : dc;
          int fr = (adr <= 1) ? dr : ((adr <= 3) ? (dr > 0 ? 2 : -2) : (dr > 0 ? 3 : -3));
          int fc = (adc <= 1) ? dc : ((adc <= 3) ? (dc > 0 ? 2 : -2) : (dc > 0 ? 3 : -3));
          int bucket = (fr + 3) * 7 + (fc + 3);
          sv = sacc[nt][e] * SCALE_Q + Rbb[i * 49 + bucket];
        } else sv = -1e30f;
        sacc[nt][e] = sv;
      }
    }

    // softmax (rows live in 16-lane groups)
    float mx[4], sm[4], inv[4];
#pragma unroll
    for (int e = 0; e < 4; e++) {
      float m = sacc[0][e];
#pragma unroll
      for (int nt = 1; nt < 13; nt++) m = fmaxf(m, sacc[nt][e]);
#pragma unroll
      for (int o = 1; o < 16; o <<= 1) m = fmaxf(m, __shfl_xor(m, o, 64));
      mx[e] = m; sm[e] = 0.f;
    }
#pragma unroll
    for (int nt = 0; nt < 13; nt++) {
#pragma unroll
      for (int e = 0; e < 4; e++) {
        float p = __expf(sacc[nt][e] - mx[e]);
        sm[e] += p;
        Pw[(q * 4 + e) * 232 + nt * 16 + c] = f2bf(p);
      }
    }
#pragma unroll
    for (int e = 0; e < 4; e++) {
      float s2 = sm[e];
#pragma unroll
      for (int o = 1; o < 16; o <<= 1) s2 += __shfl_xor(s2, o, 64);
      inv[e] = 1.f / s2;
    }

    // P x V
#pragma unroll
    for (int n2 = 0; n2 < 2; n2++) {
      f32x4 oacc = {0.f, 0.f, 0.f, 0.f};
#pragma unroll
      for (int kt = 0; kt < 7; kt++) {
        short8 pa = *(const short8*)&Pw[c * 232 + kt * 32 + q * 8];
        short8 vb = *(const short8*)&Vt[(n2 * 16 + c) * 232 + kt * 32 + q * 8];
        oacc = __builtin_amdgcn_mfma_f32_16x16x32_bf16(pa, vb, oacc, 0, 0, 0);
      }
#pragma unroll
      for (int e = 0; e < 4; e++) {
        int i = i0 + e;
        if (i < 196) {
          int d = n2 * 16 + c;
          AO[((size_t)b * NPOS + i) * DM + h * 32 + d] = f2bf(oacc[e] * inv[e]);
        }
      }
    }
  }
}

// ---------------------------------------------------------------------------
// BN over (batch, dmodel) per position n: stats -> scale/shift
// ---------------------------------------------------------------------------
__global__ __launch_bounds__(256) void bn1_stats_k(
    const float* __restrict__ T3, const float* __restrict__ bw,
    const float* __restrict__ bbb, float* __restrict__ scaleArr,
    float* __restrict__ shiftArr)
{
  int n = blockIdx.x; int tid = threadIdx.x;
  float s = 0.f, sq = 0.f;
  for (int b2 = 0; b2 < B_; b2++) {
    const float* p = T3 + ((size_t)b2 * NPOS + n) * DM;
    for (int d = tid; d < DM; d += 256) { float v = p[d]; s += v; sq += v * v; }
  }
#pragma unroll
  for (int o = 1; o < 64; o <<= 1) { s += __shfl_xor(s, o, 64); sq += __shfl_xor(sq, o, 64); }
  __shared__ float ls[4], lq[4];
  int wv = tid >> 6, ln = tid & 63;
  if (ln == 0) { ls[wv] = s; lq[wv] = sq; }
  __syncthreads();
  if (tid == 0) {
    float S = ls[0] + ls[1] + ls[2] + ls[3];
    float Q = lq[0] + lq[1] + lq[2] + lq[3];
    float mu = S / 49152.f;
    float var = Q / 49152.f - mu * mu;
    float rs = rsqrtf(var + 2e-5f);
    float sc = rs * bw[n];
    scaleArr[n] = sc;
    shiftArr[n] = bbb[n] - mu * sc;
  }
}

__global__ __launch_bounds__(256) void bn1_apply_k(
    const float* __restrict__ T3, const float* __restrict__ scaleArr,
    const float* __restrict__ shiftArr, u16* __restrict__ outb)
{
  int idx = blockIdx.x * 256 + threadIdx.x;           // float4 index
  if (idx >= MT * DM / 4) return;
  int n = (idx / 96) % NPOS;
  float4 v = *(const float4*)(T3 + (size_t)idx * 4);
  float sc = scaleArr[n], sh = shiftArr[n];
  uint32_t p0 = (uint32_t)f2bf(v.x * sc + sh) | ((uint32_t)f2bf(v.y * sc + sh) << 16);
  uint32_t p1 = (uint32_t)f2bf(v.z * sc + sh) | ((uint32_t)f2bf(v.w * sc + sh) << 16);
  ((uint2*)outb)[idx] = make_uint2(p0, p1);
}

// ---------------------------------------------------------------------------
// split-K reduce for lin head + bias
// ---------------------------------------------------------------------------
__global__ __launch_bounds__(256) void lin_reduce_k(
    const float* __restrict__ part, const float* __restrict__ lb,
    float* __restrict__ y)
{
  int idx = blockIdx.x * 256 + threadIdx.x;
  if (idx >= 128 * DM) return;
  int col = idx % DM;
  float s = lb[col];
#pragma unroll
  for (int sp = 0; sp < 49; sp++) s += part[(size_t)sp * (128 * DM) + idx];
  y[idx] = s;
}

// ---------------------------------------------------------------------------
// BN over batch (128) per feature col, in-place on y
// ---------------------------------------------------------------------------
__global__ __launch_bounds__(64) void bn2_k(
    float* __restrict__ y, const float* __restrict__ w,
    const float* __restrict__ bb)
{
  int col = blockIdx.x; int ln = threadIdx.x;
  float v0 = y[(size_t)ln * DM + col];
  float v1 = y[(size_t)(ln + 64) * DM + col];
  float s = v0 + v1, sq = v0 * v0 + v1 * v1;
#pragma unroll
  for (int o = 1; o < 64; o <<= 1) { s += __shfl_xor(s, o, 64); sq += __shfl_xor(sq, o, 64); }
  float mu = s / 128.f;
  float var = sq / 128.f - mu * mu;
  float rs = rsqrtf(var + 2e-5f);
  float sc = rs * w[col], sh = bb[col] - mu * sc;
  y[(size_t)ln * DM + col] = v0 * sc + sh;
  y[(size_t)(ln + 64) * DM + col] = v1 * sc + sh;
}

// ---------------------------------------------------------------------------
// f32 -> bf16 cast (vectorized, grid-stride over float4)
// ---------------------------------------------------------------------------
__global__ __launch_bounds__(256) void castv_k(
    const float* __restrict__ s, u16* __restrict__ d, int n4)
{
  int idx = blockIdx.x * 256 + threadIdx.x;
  int stride = gridDim.x * 256;
  for (; idx < n4; idx += stride) {
    float4 v = *(const float4*)(s + (size_t)idx * 4);
    uint32_t p0 = (uint32_t)f2bf(v.x) | ((uint32_t)f2bf(v.y) << 16);
    uint32_t p1 = (uint32_t)f2bf(v.z) | ((uint32_t)f2bf(v.w) << 16);
    ((uint2*)d)[idx] = make_uint2(p0, p1);
  }
}

// ---------------------------------------------------------------------------
// Orchestration
// ---------------------------------------------------------------------------
extern "C" void kernel_launch(void* const* d_in, const int* in_sizes, int n_in,
                              void* d_out, int out_size, void* d_ws, size_t ws_size,
                              hipStream_t stream)
{
  (void)in_sizes; (void)n_in; (void)out_size;
  const float* x    = (const float*)d_in[0];
  const float* fc1w = (const float*)d_in[1];
  const float* fc1b = (const float*)d_in[2];
  const float* fc2w = (const float*)d_in[3];
  const float* fc2b = (const float*)d_in[4];
  const float* pcw  = (const float*)d_in[5];
  const float* pcb  = (const float*)d_in[6];
  const float* ln1w = (const float*)d_in[7];
  const float* ln1b = (const float*)d_in[8];
  const float* qkvw = (const float*)d_in[9];
  const float* rpet = (const float*)d_in[10];
  const float* projw= (const float*)d_in[11];
  const float* projb= (const float*)d_in[12];
  const float* ln2w = (const float*)d_in[13];
  const float* ln2b = (const float*)d_in[14];
  const float* m1w  = (const float*)d_in[15];
  const float* m1b  = (const float*)d_in[16];
  const float* m2w  = (const float*)d_in[17];
  const float* m2b  = (const float*)d_in[18];
  const float* bn1w = (const float*)d_in[19];
  const float* bn1b = (const float*)d_in[20];
  const float* linw = (const float*)d_in[21];
  const float* linb = (const float*)d_in[22];
  const float* bn2w = (const float*)d_in[23];
  const float* bn2b = (const float*)d_in[24];
  float* y = (float*)d_out;

  // -------- aliased workspace layout (regions share by liveness) ----------
  // RA: At (transpose->fc1) / Rb (rpe->attn) / MLP1 (mlp1->mlp2) / linWb (cast->lin)
  // RB: U (fc1->fc2) / QKV (qkv->attn) / T3nb (bn1->lin)
  // RC: H (ln1->qkv) / AO (attn->proj) / H2 (ln2->mlp1)
  // RD: T0 (fc2->conv) / T2 (proj->mlp2)
  // RE: T1 (conv->proj) / T3 (mlp2->bn1)
  const size_t RA = 0;                      // 77,070,336
  const size_t RB = 77070336;               // 57,802,752
  const size_t RC = RB + 57802752;          // 19,267,584
  const size_t RD = RC + 19267584;          // 38,535,168
  const size_t RE = RD + 38535168;          // 38,535,168
  const size_t RF = RE + 38535168;          // PART 9,633,792
  const size_t RG = RF + 9633792;           // small bf16 weights 6,422,528
  const size_t RS = RG + 6422528;           // bn1 scale/shift
  const size_t NEED = RS + 4096;
  if (ws_size < NEED) return;               // insufficient scratch: bail

  char* ws = (char*)d_ws;
  u16*   At    = (u16*)(ws + RA);
  float* Rb    = (float*)(ws + RA);
  u16*   MLP1  = (u16*)(ws + RA);
  u16*   linwb = (u16*)(ws + RA);
  u16*   U     = (u16*)(ws + RB);
  u16*   QKV   = (u16*)(ws + RB);
  u16*   T3nb  = (u16*)(ws + RB);
  u16*   H     = (u16*)(ws + RC);
  u16*   AO    = (u16*)(ws + RC);
  u16*   H2    = (u16*)(ws + RC);
  float* T0    = (float*)(ws + RD);
  float* T2    = (float*)(ws + RD);
  float* T1    = (float*)(ws + RE);
  float* T3    = (float*)(ws + RE);
  float* PART  = (float*)(ws + RF);
  u16*   wb_fc1 = (u16*)(ws + RG);
  u16*   wb_fc2 = wb_fc1 + 1048576;
  u16*   wb_qkv = wb_fc2 + 393216;
  u16*   wb_proj= wb_qkv + 442368;
  u16*   wb_m1  = wb_proj + 147456;
  u16*   wb_m2  = wb_m1 + 589824;
  float* bnS  = (float*)(ws + RS);
  float* bnSh = bnS + 196;

  // weight casts (f32 -> bf16)
  castv_k<<<256, 256, 0, stream>>>(fc1w, wb_fc1, 262144);
  castv_k<<<128, 256, 0, stream>>>(fc2w, wb_fc2, 98304);
  castv_k<<<128, 256, 0, stream>>>(qkvw, wb_qkv, 110592);
  castv_k<<< 64, 256, 0, stream>>>(projw, wb_proj, 36864);
  castv_k<<<160, 256, 0, stream>>>(m1w, wb_m1, 147456);
  castv_k<<<160, 256, 0, stream>>>(m2w, wb_m2, 147456);

  // x (B,CIN,N) -> At (B*N, CIN) bf16
  transpose_cast_k<<<dim3(32, 7, 128), dim3(32, 8), 0, stream>>>(x, At);

  // embed fc1: U = relu6(At @ fc1w^T + b)   [25088 x 1024]
  gemm_k<0><<<196 * 8, 256, 0, stream>>>(At, wb_fc1, fc1b, nullptr, U,
                                          MT, 1024, 1024, 1024, 1024, 8, 0);
  // embed fc2: T0 = U @ fc2w^T + b          [25088 x 384] f32
  gemm_k<1><<<196 * 3, 256, 0, stream>>>(U, wb_fc2, fc2b, nullptr, T0,
                                          MT, 384, 1024, 1024, 1024, 3, 0);
  // depthwise conv + bias + residual -> T1
  conv_res_k<<<(B_ * NPOS * 96 + 255) / 256, 256, 0, stream>>>(T0, pcw, pcb, T1);
  // LN1 -> H (bf16)
  ln_k<<<MT / 4, 256, 0, stream>>>(T1, ln1w, ln1b, H);
  // qkv: QKV = H @ qkvw^T (no bias)          [25088 x 1152] bf16
  gemm_k<2><<<196 * 9, 256, 0, stream>>>(H, wb_qkv, nullptr, nullptr, QKV,
                                          MT, 1152, 384, 384, 384, 9, 0);
  // rpe scores (scale folded)
  rpe_k<<<1536, 256, 0, stream>>>(QKV, rpet, Rb);
  // fused attention -> AO (bf16)
  attn_k<<<1536, 256, 0, stream>>>(QKV, Rb, AO);
  // proj + residual(T1) -> T2 (f32)
  gemm_k<3><<<196 * 3, 256, 0, stream>>>(AO, wb_proj, projb, T1, T2,
                                          MT, 384, 384, 384, 384, 3, 0);
  // LN2 -> H2 (bf16)
  ln_k<<<MT / 4, 256, 0, stream>>>(T2, ln2w, ln2b, H2);
  // mlp fc1: MLP1 = relu6(H2 @ m1w^T + b)    [25088 x 1536] bf16
  gemm_k<0><<<196 * 12, 256, 0, stream>>>(H2, wb_m1, m1b, nullptr, MLP1,
                                           MT, 1536, 384, 384, 384, 12, 0);
  // mlp fc2 + residual(T2) -> T3 (f32)
  gemm_k<3><<<196 * 3, 256, 0, stream>>>(MLP1, wb_m2, m2b, T2, T3,
                                          MT, 384, 1536, 1536, 1536, 3, 0);
  // cast lin_w -> bf16 (after MLP1 dead; shares region A)
  castv_k<<<2048, 256, 0, stream>>>(linw, linwb, 7225344);
  // BN1 (per position) -> T3nb (bf16)
  bn1_stats_k<<<196, 256, 0, stream>>>(T3, bn1w, bn1b, bnS, bnSh);
  bn1_apply_k<<<(MT * DM / 4 + 255) / 256, 256, 0, stream>>>(T3, bnS, bnSh, T3nb);
  // lin head: y = T3nb(128 x 75264) @ linw^T, split-K 49 x 1536
  gemm_k<4><<<3 * 49, 256, 0, stream>>>(T3nb, linwb, nullptr, nullptr, PART,
                                         128, 384, 1536, 75264, 75264, 3, 1536);
  lin_reduce_k<<<192, 256, 0, stream>>>(PART, linb, y);
  // BN2 (per feature over batch), in place on d_out
  bn2_k<<<384, 64, 0, stream>>>(y, bn2w, bn2b);
}

// Round 2
// 972.886 us; speedup vs baseline: 1.0728x; 1.0728x over previous
//
#include <hip/hip_runtime.h>
#include <cstdint>

// ---------------------------------------------------------------------------
// Problem constants
// ---------------------------------------------------------------------------
#define B_    128
#define CIN   1024
#define NPOS  196          // 14*14
#define DM    384
#define NH_   12
#define HD_   32
#define DFF_  1536
#define MT    25088        // B_*NPOS
#define SCALE_Q 0.17677669529663687f   // 1/sqrt(32)

typedef unsigned short u16;
typedef __attribute__((ext_vector_type(8))) short  short8;   // 8 bf16 (4 VGPR)
typedef __attribute__((ext_vector_type(4))) float  f32x4;    // MFMA C/D

__device__ __forceinline__ u16 f2bf(float f) {
  union { float f; uint32_t u; } v; v.f = f;
  uint32_t u = v.u;
  return (u16)((u + 0x7fffu + ((u >> 16) & 1u)) >> 16);
}
__device__ __forceinline__ float bf2f(u16 h) {
  union { uint32_t u; float f; } v; v.u = ((uint32_t)h) << 16;
  return v.f;
}

#define GLDS16(g, l)                                                           \
  __builtin_amdgcn_global_load_lds(                                            \
      (const __attribute__((address_space(1))) void*)(g),                      \
      (__attribute__((address_space(3))) void*)(l), 16, 0, 0)

// ---------------------------------------------------------------------------
// Generic bf16 MFMA GEMM:  out = epi( A[M x K] * W[N x K]^T )
// 128x128 tile, 4 waves (2x2 of 64x64), BK=32, 16 MFMA / K-step.
// MODE: 0 = bias+relu6 -> bf16   (fc1, mlp1)
//       1 = bias       -> f32    (fc2)
//       2 = plain      -> bf16   (qkv)
//       3 = bias+res   -> f32    (proj, mlp2)
//       4 = split-K partial -> f32 (lin head; W is f32, converted in staging)
// ---------------------------------------------------------------------------
template <int MODE>
__global__ __launch_bounds__(256) void gemm_k(
    const u16* __restrict__ A, const void* __restrict__ Wv,
    const float* __restrict__ bias, const float* __restrict__ res,
    void* __restrict__ outp,
    int M, int N, int K, int lda, int ldw, int nTN, int splitK)
{
  __shared__ __align__(16) u16 As[4 * 128 * 8];
  __shared__ __align__(16) u16 Bs[4 * 128 * 8];

  int bid = blockIdx.x;
  int split = 0, mT, nT;
  if (MODE == 4) { split = bid / nTN; nT = bid % nTN; mT = 0; }
  else           { mT = bid / nTN;    nT = bid % nTN; }

  const u16* Ab = A + (size_t)split * splitK;
  float* outF = (float*)outp + ((MODE == 4) ? (size_t)split * (size_t)M * N : (size_t)0);
  u16*   outU = (u16*)outp;

  int tid = threadIdx.x;
  int wv = tid >> 6, ln = tid & 63;
  int q = ln >> 4, c = ln & 15;
  int wr = wv >> 1, wc = wv & 1;
  int mBase = mT * 128, nBase = nT * 128;

  f32x4 acc[4][4];
#pragma unroll
  for (int i = 0; i < 4; i++)
#pragma unroll
    for (int j = 0; j < 4; j++) acc[i][j] = (f32x4){0.f, 0.f, 0.f, 0.f};

  const u16* Ag = Ab + (size_t)mBase * lda;
  const u16*  Wg16 = (const u16*)Wv + (size_t)split * splitK + (size_t)nBase * ldw;
  const float* Wg32 = (const float*)Wv + (size_t)split * splitK + (size_t)nBase * ldw;

  for (int k0 = 0; k0 < K; k0 += 32) {
    // ---- stage 8KB A-tile + 8KB W-tile ----
#pragma unroll
    for (int i = 0; i < 2; i++) {
      int ch = wv * 2 + i;             // chunk 0..7 (1024B each)
      int s = ch >> 1;                 // k-slot (8 bf16)
      int r = (ch & 1) * 64 + ln;      // tile row
      GLDS16(Ag + (size_t)r * lda + (k0 + s * 8), &As[ch * 512]);
      if constexpr (MODE == 4) {
        const float* wp = Wg32 + (size_t)r * ldw + (k0 + s * 8);
        float4 f0 = *(const float4*)wp, f1 = *(const float4*)(wp + 4);
        short8 pk;
        pk[0] = (short)f2bf(f0.x); pk[1] = (short)f2bf(f0.y);
        pk[2] = (short)f2bf(f0.z); pk[3] = (short)f2bf(f0.w);
        pk[4] = (short)f2bf(f1.x); pk[5] = (short)f2bf(f1.y);
        pk[6] = (short)f2bf(f1.z); pk[7] = (short)f2bf(f1.w);
        *(short8*)&Bs[ch * 512 + ln * 8] = pk;
      } else {
        GLDS16(Wg16 + (size_t)r * ldw + (k0 + s * 8), &Bs[ch * 512]);
      }
    }
    __syncthreads();
    short8 afr[4], bfr[4];
#pragma unroll
    for (int mt2 = 0; mt2 < 4; mt2++)
      afr[mt2] = *(const short8*)&As[((q * 128) + wr * 64 + mt2 * 16 + c) * 8];
#pragma unroll
    for (int nt2 = 0; nt2 < 4; nt2++)
      bfr[nt2] = *(const short8*)&Bs[((q * 128) + wc * 64 + nt2 * 16 + c) * 8];
#pragma unroll
    for (int mt2 = 0; mt2 < 4; mt2++)
#pragma unroll
      for (int nt2 = 0; nt2 < 4; nt2++)
        acc[mt2][nt2] = __builtin_amdgcn_mfma_f32_16x16x32_bf16(
            afr[mt2], bfr[nt2], acc[mt2][nt2], 0, 0, 0);
    __syncthreads();
  }

  // ---- epilogue ----
#pragma unroll
  for (int mt2 = 0; mt2 < 4; mt2++) {
    int row0 = mBase + wr * 64 + mt2 * 16 + q * 4;
#pragma unroll
    for (int nt2 = 0; nt2 < 4; nt2++) {
      int col = nBase + wc * 64 + nt2 * 16 + c;
      float bv = (MODE == 0 || MODE == 1 || MODE == 3) ? bias[col] : 0.f;
      f32x4 v = acc[mt2][nt2];
#pragma unroll
      for (int e = 0; e < 4; e++) {
        int row = row0 + e;
        float x = v[e] + bv;
        if (MODE == 0) x = fminf(fmaxf(x, 0.f), 6.f);
        if (MODE == 3) x += res[(size_t)row * N + col];
        if (MODE == 0 || MODE == 2) outU[(size_t)row * N + col] = f2bf(x);
        else                        outF[(size_t)row * N + col] = x;
      }
    }
  }
}

// ---------------------------------------------------------------------------
// x (B, CIN, HW, HW) f32  ->  A_t (B*NPOS, CIN) bf16
// ---------------------------------------------------------------------------
__global__ __launch_bounds__(256) void transpose_cast_k(
    const float* __restrict__ x, u16* __restrict__ At)
{
  __shared__ float t[32][33];
  int c0 = blockIdx.x * 32, n0 = blockIdx.y * 32, b = blockIdx.z;
  int tx = threadIdx.x, ty = threadIdx.y;
  const float* xb = x + (size_t)b * CIN * NPOS;
#pragma unroll
  for (int i = 0; i < 4; i++) {
    int cc = c0 + ty + i * 8, nn = n0 + tx;
    t[ty + i * 8][tx] = (nn < NPOS) ? xb[(size_t)cc * NPOS + nn] : 0.f;
  }
  __syncthreads();
  u16* Ab = At + (size_t)b * NPOS * CIN;
#pragma unroll
  for (int i = 0; i < 4; i++) {
    int nn = n0 + ty + i * 8, cc = c0 + tx;
    if (nn < NPOS) Ab[(size_t)nn * CIN + cc] = f2bf(t[tx][ty + i * 8]);
  }
}

// ---------------------------------------------------------------------------
// depthwise 3x3 SAME conv + bias + identity residual (fp32)
// ---------------------------------------------------------------------------
__global__ __launch_bounds__(256) void conv_res_k(
    const float* __restrict__ T0, const float* __restrict__ pcw,
    const float* __restrict__ pcb, float* __restrict__ T1)
{
  int idx = blockIdx.x * 256 + threadIdx.x;
  if (idx >= B_ * NPOS * 96) return;
  int d4 = idx % 96; int rem = idx / 96;
  int n = rem % NPOS; int b = rem / NPOS;
  int hh = n / 14, ww = n % 14;
  int d0 = d4 * 4;
  float w9[4][9];
#pragma unroll
  for (int j = 0; j < 4; j++)
#pragma unroll
    for (int t = 0; t < 9; t++) w9[j][t] = pcw[(d0 + j) * 9 + t];
  const float* base = T0 + (size_t)b * NPOS * DM;
  float4 ctr = *(const float4*)(base + (size_t)n * DM + d0);
  float ax = ctr.x + pcb[d0], ay = ctr.y + pcb[d0 + 1];
  float az = ctr.z + pcb[d0 + 2], aw = ctr.w + pcb[d0 + 3];
#pragma unroll
  for (int kh = 0; kh < 3; kh++) {
    int h2 = hh + kh - 1;
    if (h2 < 0 || h2 >= 14) continue;
#pragma unroll
    for (int kw = 0; kw < 3; kw++) {
      int w2 = ww + kw - 1;
      if (w2 < 0 || w2 >= 14) continue;
      float4 v = *(const float4*)(base + (size_t)(h2 * 14 + w2) * DM + d0);
      int t = kh * 3 + kw;
      ax += v.x * w9[0][t]; ay += v.y * w9[1][t];
      az += v.z * w9[2][t]; aw += v.w * w9[3][t];
    }
  }
  float4 o = {ax, ay, az, aw};
  *(float4*)(T1 + (size_t)b * NPOS * DM + (size_t)n * DM + d0) = o;
}

// ---------------------------------------------------------------------------
// LayerNorm(384) f32 -> bf16, one wave per row
// ---------------------------------------------------------------------------
__global__ __launch_bounds__(256) void ln_k(
    const float* __restrict__ in, const float* __restrict__ w,
    const float* __restrict__ bb, u16* __restrict__ out)
{
  int row = blockIdx.x * 4 + (threadIdx.x >> 6);
  int ln = threadIdx.x & 63;
  const float* r = in + (size_t)row * DM;
  float v[6]; float s = 0.f, sq = 0.f;
#pragma unroll
  for (int j = 0; j < 6; j++) { v[j] = r[ln + 64 * j]; s += v[j]; sq += v[j] * v[j]; }
#pragma unroll
  for (int o = 1; o < 64; o <<= 1) { s += __shfl_xor(s, o, 64); sq += __shfl_xor(sq, o, 64); }
  float mu = s * (1.f / 384.f);
  float var = sq * (1.f / 384.f) - mu * mu;
  float rs = rsqrtf(var + 1e-5f);
  u16* orow = out + (size_t)row * DM;
#pragma unroll
  for (int j = 0; j < 6; j++) { int d = ln + 64 * j; orow[d] = f2bf((v[j] - mu) * rs * w[d] + bb[d]); }
}

// ---------------------------------------------------------------------------
// rpe_scores[b,h,i,t] = SCALE_Q * sum_d q[b,h,i,d] * table[d,t]   (fp32)
// ---------------------------------------------------------------------------
__global__ __launch_bounds__(256) void rpe_k(
    const u16* __restrict__ QKV, const float* __restrict__ tabG,
    float* __restrict__ Rb)
{
  __shared__ float qs[NPOS * 32];
  __shared__ float tab[32 * 49];
  int bh = blockIdx.x; int b = bh / NH_, h = bh % NH_;
  int tid = threadIdx.x;
  size_t qoff = (size_t)b * NPOS * 1152 + h * 32;
  for (int idx = tid; idx < NPOS * 32; idx += 256) {
    int n = idx >> 5, d = idx & 31;
    qs[idx] = bf2f(QKV[qoff + (size_t)n * 1152 + d]);
  }
  for (int idx = tid; idx < 32 * 49; idx += 256) tab[idx] = tabG[idx];
  __syncthreads();
  for (int idx = tid; idx < NPOS * 49; idx += 256) {
    int i = idx / 49, t = idx - i * 49;
    float s = 0.f;
#pragma unroll
    for (int d = 0; d < 32; d++) s += qs[i * 32 + d] * tab[d * 49 + t];
    Rb[(size_t)bh * 9604 + idx] = s * SCALE_Q;
  }
}

// ---------------------------------------------------------------------------
// Fused attention per (b,h). K staged once into LDS fragment layout
// Ks[4][196][8] (global_load_lds); V^T staged into Vt[32][232] (zero-padded);
// per-wave P strip in fragment layout Psf[26][16][8] + shared 256B zero pad.
// LDS = 12544 + 14848 + 4*6656 + 256 = 54272 B -> 3 blocks/CU.
// ---------------------------------------------------------------------------
__global__ __launch_bounds__(256) void attn_k(
    const u16* __restrict__ QKV, const float* __restrict__ Rb,
    u16* __restrict__ AO)
{
  __shared__ __align__(16) u16 Ks[4 * 196 * 8];    // [s][j][e]
  __shared__ __align__(16) u16 Vt[32 * 232];       // [d][j], pad j>=196 zero
  __shared__ __align__(16) u16 Psf[4][26 * 16 * 8];// per-wave [slot][i][e]
  __shared__ __align__(16) u16 Pz[128];            // 16 lanes x 8 zeros
  int bh = blockIdx.x; int b = bh / NH_, h = bh % NH_;
  int tid = threadIdx.x;
  int wv = tid >> 6, ln = tid & 63;
  int q = ln >> 4, c = ln & 15;
  size_t rowbase = (size_t)b * NPOS * 1152 + h * 32;

  // ---- stage K fragments via global_load_lds (wave-uniform dest) ----
  for (int cb = wv * 64; cb < 784; cb += 256) {
    int ch = cb + ln;
    if (ch < 784) {
      int s = ch / 196, j = ch - s * 196;
      GLDS16(QKV + rowbase + 384 + (size_t)j * 1152 + s * 8, &Ks[cb * 8]);
    }
  }
  // ---- stage V transposed; zero pad cols ----
  for (int idx = tid; idx < NPOS * 32; idx += 256) {
    int nn = idx >> 5, d = idx & 31;
    Vt[d * 232 + nn] = QKV[rowbase + 768 + (size_t)nn * 1152 + d];
  }
  for (int idx = tid; idx < 32 * 36; idx += 256) {
    int d = idx / 36, jj = idx - d * 36;
    Vt[d * 232 + 196 + jj] = 0;
  }
  for (int idx = tid; idx < 128; idx += 256) Pz[idx] = 0;
  __syncthreads();

  const float* Rbb = Rb + (size_t)bh * 9604;
  u16* Pw = Psf[wv];

  for (int mt = wv; mt < 13; mt += 4) {
    int mb = mt * 16;
    int irow = mb + c; if (irow > 195) irow = 195;
    short8 afrag = *(const short8*)(QKV + rowbase + (size_t)irow * 1152 + q * 8);
    int i0 = mb + q * 4;

    f32x4 sacc[13];
#pragma unroll
    for (int nt = 0; nt < 13; nt++) {
      int jc = nt * 16 + c; if (jc > 195) jc = 195;
      short8 bfrag = *(const short8*)&Ks[(q * 196 + jc) * 8];
      f32x4 z = {0.f, 0.f, 0.f, 0.f};
      sacc[nt] = __builtin_amdgcn_mfma_f32_16x16x32_bf16(afrag, bfrag, z, 0, 0, 0);
    }

    // scale + bucket bias + mask (row/col decompositions hoisted)
    int ri4[4], ci4[4];
#pragma unroll
    for (int e = 0; e < 4; e++) {
      int i = i0 + e; int ri = i / 14;
      ri4[e] = ri; ci4[e] = i - ri * 14;
    }
#pragma unroll
    for (int nt = 0; nt < 13; nt++) {
      int j = nt * 16 + c;
      int rj = j / 14, cj = j - rj * 14;
      bool jok = (j < 196);
#pragma unroll
      for (int e = 0; e < 4; e++) {
        int i = i0 + e;
        float sv = -1e30f;
        if (jok && i < 196) {
          int dr = ri4[e] - rj, dc = ci4[e] - cj;
          int adr = dr < 0 ? -dr : dr, adc = dc < 0 ? -dc : dc;
          int tr = adr <= 1 ? adr : (adr <= 3 ? 2 : 3);
          int tc = adc <= 1 ? adc : (adc <= 3 ? 2 : 3);
          int fr = dr < 0 ? -tr : tr, fc = dc < 0 ? -tc : tc;
          int bucket = fr * 7 + fc + 24;
          sv = sacc[nt][e] * SCALE_Q + Rbb[i * 49 + bucket];
        }
        sacc[nt][e] = sv;
      }
    }

    // softmax (rows live in 16-lane groups)
    float mx[4], sm[4], inv[4];
#pragma unroll
    for (int e = 0; e < 4; e++) {
      float m = sacc[0][e];
#pragma unroll
      for (int nt = 1; nt < 13; nt++) m = fmaxf(m, sacc[nt][e]);
#pragma unroll
      for (int o = 1; o < 16; o <<= 1) m = fmaxf(m, __shfl_xor(m, o, 64));
      mx[e] = m; sm[e] = 0.f;
    }
#pragma unroll
    for (int nt = 0; nt < 13; nt++) {
#pragma unroll
      for (int e = 0; e < 4; e++) {
        float p = __expf(sacc[nt][e] - mx[e]);
        sm[e] += p;
        Pw[(nt * 2 + (c >> 3)) * 128 + (q * 4 + e) * 8 + (c & 7)] = f2bf(p);
      }
    }
#pragma unroll
    for (int e = 0; e < 4; e++) {
      float s2 = sm[e];
#pragma unroll
      for (int o = 1; o < 16; o <<= 1) s2 += __shfl_xor(s2, o, 64);
      inv[e] = 1.f / s2;
    }

    // P x V  (A-frag from Psf; k-tail slots 26,27 read shared zeros)
#pragma unroll
    for (int n2 = 0; n2 < 2; n2++) {
      f32x4 oacc = {0.f, 0.f, 0.f, 0.f};
#pragma unroll
      for (int kt = 0; kt < 7; kt++) {
        int ps = kt * 4 + q;
        const u16* pap = (ps < 26) ? &Pw[ps * 128 + c * 8] : &Pz[c * 8];
        short8 pa = *(const short8*)pap;
        short8 vb = *(const short8*)&Vt[(n2 * 16 + c) * 232 + kt * 32 + q * 8];
        oacc = __builtin_amdgcn_mfma_f32_16x16x32_bf16(pa, vb, oacc, 0, 0, 0);
      }
#pragma unroll
      for (int e = 0; e < 4; e++) {
        int i = i0 + e;
        if (i < 196) {
          int d = n2 * 16 + c;
          AO[((size_t)b * NPOS + i) * DM + h * 32 + d] = f2bf(oacc[e] * inv[e]);
        }
      }
    }
  }
}

// ---------------------------------------------------------------------------
// BN1 over (batch, dmodel) per position n: two-stage stats
// ---------------------------------------------------------------------------
__global__ __launch_bounds__(256) void bn1_partial_k(
    const float* __restrict__ T3, float* __restrict__ part)
{
  int n = blockIdx.x >> 3, g = blockIdx.x & 7;
  int tid = threadIdx.x;
  float s = 0.f, sq = 0.f;
  for (int b2 = g * 16; b2 < g * 16 + 16; b2++) {
    const float* p = T3 + ((size_t)b2 * NPOS + n) * DM;
    for (int d = tid; d < DM; d += 256) { float v = p[d]; s += v; sq += v * v; }
  }
#pragma unroll
  for (int o = 1; o < 64; o <<= 1) { s += __shfl_xor(s, o, 64); sq += __shfl_xor(sq, o, 64); }
  __shared__ float ls[4], lq[4];
  int wv = tid >> 6, ln = tid & 63;
  if (ln == 0) { ls[wv] = s; lq[wv] = sq; }
  __syncthreads();
  if (tid == 0) {
    part[blockIdx.x * 2]     = ls[0] + ls[1] + ls[2] + ls[3];
    part[blockIdx.x * 2 + 1] = lq[0] + lq[1] + lq[2] + lq[3];
  }
}

__global__ __launch_bounds__(256) void bn1_finish_k(
    const float* __restrict__ part, const float* __restrict__ bw,
    const float* __restrict__ bbb, float* __restrict__ scaleArr,
    float* __restrict__ shiftArr)
{
  int n = threadIdx.x;
  if (n >= NPOS) return;
  float S = 0.f, Q = 0.f;
#pragma unroll
  for (int g = 0; g < 8; g++) { S += part[(n * 8 + g) * 2]; Q += part[(n * 8 + g) * 2 + 1]; }
  float mu = S / 49152.f;
  float var = Q / 49152.f - mu * mu;
  float rs = rsqrtf(var + 2e-5f);
  float sc = rs * bw[n];
  scaleArr[n] = sc;
  shiftArr[n] = bbb[n] - mu * sc;
}

__global__ __launch_bounds__(256) void bn1_apply_k(
    const float* __restrict__ T3, const float* __restrict__ scaleArr,
    const float* __restrict__ shiftArr, u16* __restrict__ outb)
{
  int idx = blockIdx.x * 256 + threadIdx.x;           // float4 index
  if (idx >= MT * DM / 4) return;
  int n = (idx / 96) % NPOS;
  float4 v = *(const float4*)(T3 + (size_t)idx * 4);
  float sc = scaleArr[n], sh = shiftArr[n];
  uint32_t p0 = (uint32_t)f2bf(v.x * sc + sh) | ((uint32_t)f2bf(v.y * sc + sh) << 16);
  uint32_t p1 = (uint32_t)f2bf(v.z * sc + sh) | ((uint32_t)f2bf(v.w * sc + sh) << 16);
  ((uint2*)outb)[idx] = make_uint2(p0, p1);
}

// ---------------------------------------------------------------------------
// split-K reduce for lin head + bias
// ---------------------------------------------------------------------------
__global__ __launch_bounds__(256) void lin_reduce_k(
    const float* __restrict__ part, const float* __restrict__ lb,
    float* __restrict__ y)
{
  int idx = blockIdx.x * 256 + threadIdx.x;
  if (idx >= 128 * DM) return;
  int col = idx % DM;
  float s = lb[col];
#pragma unroll
  for (int sp = 0; sp < 49; sp++) s += part[(size_t)sp * (128 * DM) + idx];
  y[idx] = s;
}

// ---------------------------------------------------------------------------
// BN2 over batch (128) per feature col, in-place on y
// ---------------------------------------------------------------------------
__global__ __launch_bounds__(64) void bn2_k(
    float* __restrict__ y, const float* __restrict__ w,
    const float* __restrict__ bb)
{
  int col = blockIdx.x; int ln = threadIdx.x;
  float v0 = y[(size_t)ln * DM + col];
  float v1 = y[(size_t)(ln + 64) * DM + col];
  float s = v0 + v1, sq = v0 * v0 + v1 * v1;
#pragma unroll
  for (int o = 1; o < 64; o <<= 1) { s += __shfl_xor(s, o, 64); sq += __shfl_xor(sq, o, 64); }
  float mu = s / 128.f;
  float var = sq / 128.f - mu * mu;
  float rs = rsqrtf(var + 2e-5f);
  float sc = rs * w[col], sh = bb[col] - mu * sc;
  y[(size_t)ln * DM + col] = v0 * sc + sh;
  y[(size_t)(ln + 64) * DM + col] = v1 * sc + sh;
}

// ---------------------------------------------------------------------------
// f32 -> bf16 cast (vectorized, grid-stride over float4)
// ---------------------------------------------------------------------------
__global__ __launch_bounds__(256) void castv_k(
    const float* __restrict__ s, u16* __restrict__ d, int n4)
{
  int idx = blockIdx.x * 256 + threadIdx.x;
  int stride = gridDim.x * 256;
  for (; idx < n4; idx += stride) {
    float4 v = *(const float4*)(s + (size_t)idx * 4);
    uint32_t p0 = (uint32_t)f2bf(v.x) | ((uint32_t)f2bf(v.y) << 16);
    uint32_t p1 = (uint32_t)f2bf(v.z) | ((uint32_t)f2bf(v.w) << 16);
    ((uint2*)d)[idx] = make_uint2(p0, p1);
  }
}

// ---------------------------------------------------------------------------
// Orchestration
// ---------------------------------------------------------------------------
extern "C" void kernel_launch(void* const* d_in, const int* in_sizes, int n_in,
                              void* d_out, int out_size, void* d_ws, size_t ws_size,
                              hipStream_t stream)
{
  (void)in_sizes; (void)n_in; (void)out_size;
  const float* x    = (const float*)d_in[0];
  const float* fc1w = (const float*)d_in[1];
  const float* fc1b = (const float*)d_in[2];
  const float* fc2w = (const float*)d_in[3];
  const float* fc2b = (const float*)d_in[4];
  const float* pcw  = (const float*)d_in[5];
  const float* pcb  = (const float*)d_in[6];
  const float* ln1w = (const float*)d_in[7];
  const float* ln1b = (const float*)d_in[8];
  const float* qkvw = (const float*)d_in[9];
  const float* rpet = (const float*)d_in[10];
  const float* projw= (const float*)d_in[11];
  const float* projb= (const float*)d_in[12];
  const float* ln2w = (const float*)d_in[13];
  const float* ln2b = (const float*)d_in[14];
  const float* m1w  = (const float*)d_in[15];
  const float* m1b  = (const float*)d_in[16];
  const float* m2w  = (const float*)d_in[17];
  const float* m2b  = (const float*)d_in[18];
  const float* bn1w = (const float*)d_in[19];
  const float* bn1b = (const float*)d_in[20];
  const float* linw = (const float*)d_in[21];
  const float* linb = (const float*)d_in[22];
  const float* bn2w = (const float*)d_in[23];
  const float* bn2b = (const float*)d_in[24];
  float* y = (float*)d_out;

  // -------- aliased workspace layout (regions share by liveness) ----------
  const size_t RA = 0;                      // At / Rb / MLP1
  const size_t RB = 77070336;               // U / QKV / T3nb
  const size_t RC = RB + 57802752;          // H / AO / H2
  const size_t RD = RC + 19267584;          // T0 / T2
  const size_t RE = RD + 38535168;          // T1 / T3
  const size_t RF = RE + 38535168;          // PART (lin split-K)
  const size_t RG = RF + 9633792;           // small bf16 weights
  const size_t RS = RG + 6422528;           // bn1 scale/shift + partials
  const size_t NEED = RS + 2048 + 16384;
  if (ws_size < NEED) return;

  char* ws = (char*)d_ws;
  u16*   At    = (u16*)(ws + RA);
  float* Rb    = (float*)(ws + RA);
  u16*   MLP1  = (u16*)(ws + RA);
  u16*   U     = (u16*)(ws + RB);
  u16*   QKV   = (u16*)(ws + RB);
  u16*   T3nb  = (u16*)(ws + RB);
  u16*   H     = (u16*)(ws + RC);
  u16*   AO    = (u16*)(ws + RC);
  u16*   H2    = (u16*)(ws + RC);
  float* T0    = (float*)(ws + RD);
  float* T2    = (float*)(ws + RD);
  float* T1    = (float*)(ws + RE);
  float* T3    = (float*)(ws + RE);
  float* PART  = (float*)(ws + RF);
  u16*   wb_fc1 = (u16*)(ws + RG);
  u16*   wb_fc2 = wb_fc1 + 1048576;
  u16*   wb_qkv = wb_fc2 + 393216;
  u16*   wb_proj= wb_qkv + 442368;
  u16*   wb_m1  = wb_proj + 147456;
  u16*   wb_m2  = wb_m1 + 589824;
  float* bnS   = (float*)(ws + RS);
  float* bnSh  = bnS + 196;
  float* bnP   = (float*)(ws + RS + 2048);

  // weight casts (f32 -> bf16)
  castv_k<<<256, 256, 0, stream>>>(fc1w, wb_fc1, 262144);
  castv_k<<<128, 256, 0, stream>>>(fc2w, wb_fc2, 98304);
  castv_k<<<128, 256, 0, stream>>>(qkvw, wb_qkv, 110592);
  castv_k<<< 64, 256, 0, stream>>>(projw, wb_proj, 36864);
  castv_k<<<160, 256, 0, stream>>>(m1w, wb_m1, 147456);
  castv_k<<<160, 256, 0, stream>>>(m2w, wb_m2, 147456);

  // x (B,CIN,N) -> At (B*N, CIN) bf16
  transpose_cast_k<<<dim3(32, 7, 128), dim3(32, 8), 0, stream>>>(x, At);

  // embed fc1: U = relu6(At @ fc1w^T + b)   [25088 x 1024]
  gemm_k<0><<<196 * 8, 256, 0, stream>>>(At, wb_fc1, fc1b, nullptr, U,
                                          MT, 1024, 1024, 1024, 1024, 8, 0);
  // embed fc2: T0 = U @ fc2w^T + b          [25088 x 384] f32
  gemm_k<1><<<196 * 3, 256, 0, stream>>>(U, wb_fc2, fc2b, nullptr, T0,
                                          MT, 384, 1024, 1024, 1024, 3, 0);
  // depthwise conv + bias + residual -> T1
  conv_res_k<<<(B_ * NPOS * 96 + 255) / 256, 256, 0, stream>>>(T0, pcw, pcb, T1);
  // LN1 -> H (bf16)
  ln_k<<<MT / 4, 256, 0, stream>>>(T1, ln1w, ln1b, H);
  // qkv: QKV = H @ qkvw^T (no bias)          [25088 x 1152] bf16
  gemm_k<2><<<196 * 9, 256, 0, stream>>>(H, wb_qkv, nullptr, nullptr, QKV,
                                          MT, 1152, 384, 384, 384, 9, 0);
  // rpe scores (scale folded)
  rpe_k<<<1536, 256, 0, stream>>>(QKV, rpet, Rb);
  // fused attention -> AO (bf16)
  attn_k<<<1536, 256, 0, stream>>>(QKV, Rb, AO);
  // proj + residual(T1) -> T2 (f32)
  gemm_k<3><<<196 * 3, 256, 0, stream>>>(AO, wb_proj, projb, T1, T2,
                                          MT, 384, 384, 384, 384, 3, 0);
  // LN2 -> H2 (bf16)
  ln_k<<<MT / 4, 256, 0, stream>>>(T2, ln2w, ln2b, H2);
  // mlp fc1: MLP1 = relu6(H2 @ m1w^T + b)    [25088 x 1536] bf16
  gemm_k<0><<<196 * 12, 256, 0, stream>>>(H2, wb_m1, m1b, nullptr, MLP1,
                                           MT, 1536, 384, 384, 384, 12, 0);
  // mlp fc2 + residual(T2) -> T3 (f32)
  gemm_k<3><<<196 * 3, 256, 0, stream>>>(MLP1, wb_m2, m2b, T2, T3,
                                          MT, 384, 1536, 1536, 1536, 3, 0);
  // BN1 (per position) -> T3nb (bf16)
  bn1_partial_k<<<196 * 8, 256, 0, stream>>>(T3, bnP);
  bn1_finish_k<<<1, 256, 0, stream>>>(bnP, bn1w, bn1b, bnS, bnSh);
  bn1_apply_k<<<(MT * DM / 4 + 255) / 256, 256, 0, stream>>>(T3, bnS, bnSh, T3nb);
  // lin head: y = T3nb(128 x 75264) @ linw^T, split-K 49 x 1536 (W f32 direct)
  gemm_k<4><<<3 * 49, 256, 0, stream>>>(T3nb, linw, nullptr, nullptr, PART,
                                         128, 384, 1536, 75264, 75264, 3, 1536);
  lin_reduce_k<<<192, 256, 0, stream>>>(PART, linb, y);
  // BN2 (per feature over batch), in place on d_out
  bn2_k<<<384, 64, 0, stream>>>(y, bn2w, bn2b);
}

// Round 3
// 921.371 us; speedup vs baseline: 1.1328x; 1.0559x over previous
//
#include <hip/hip_runtime.h>
#include <cstdint>

// ---------------------------------------------------------------------------
// Problem constants
// ---------------------------------------------------------------------------
#define B_    128
#define CIN   1024
#define NPOS  196          // 14*14
#define DM    384
#define NH_   12
#define HD_   32
#define DFF_  1536
#define MT    25088        // B_*NPOS
#define SCALE_Q 0.17677669529663687f   // 1/sqrt(32)

typedef unsigned short u16;
typedef __attribute__((ext_vector_type(8))) short  short8;   // 8 bf16 (4 VGPR)
typedef __attribute__((ext_vector_type(4))) float  f32x4;    // MFMA C/D

__device__ __forceinline__ u16 f2bf(float f) {
  union { float f; uint32_t u; } v; v.f = f;
  uint32_t u = v.u;
  return (u16)((u + 0x7fffu + ((u >> 16) & 1u)) >> 16);
}
__device__ __forceinline__ float bf2f(u16 h) {
  union { uint32_t u; float f; } v; v.u = ((uint32_t)h) << 16;
  return v.f;
}

#define GLDS16(g, l)                                                           \
  __builtin_amdgcn_global_load_lds(                                            \
      (const __attribute__((address_space(1))) void*)(g),                      \
      (__attribute__((address_space(3))) void*)(l), 16, 0, 0)

// ---------------------------------------------------------------------------
// Generic bf16 MFMA GEMM:  out = epi( A[M x K] * W[N x K]^T )
// 128x128 tile, 4 waves (2x2 of 64x64), BK=64, 32 MFMA / K-step.
// MODE: 0 = bias+relu6 -> bf16   (fc1, mlp1)
//       1 = bias       -> f32    (fc2)
//       2 = plain      -> bf16   (qkv)
//       3 = bias+res   -> f32    (proj, mlp2)
//       4 = split-K partial -> f32 (lin head; W is f32, converted in staging)
// ---------------------------------------------------------------------------
template <int MODE>
__global__ __launch_bounds__(256) void gemm_k(
    const u16* __restrict__ A, const void* __restrict__ Wv,
    const float* __restrict__ bias, const float* __restrict__ res,
    void* __restrict__ outp,
    int M, int N, int K, int lda, int ldw, int nTN, int splitK)
{
  __shared__ __align__(16) u16 As[8 * 128 * 8];   // [s][r][8], s = k-slot (8 bf16)
  __shared__ __align__(16) u16 Bs[8 * 128 * 8];

  int bid = blockIdx.x;
  int split = 0, mT, nT;
  if (MODE == 4) { split = bid / nTN; nT = bid % nTN; mT = 0; }
  else           { mT = bid / nTN;    nT = bid % nTN; }

  const u16* Ab = A + (size_t)split * splitK;
  float* outF = (float*)outp + ((MODE == 4) ? (size_t)split * (size_t)M * N : (size_t)0);
  u16*   outU = (u16*)outp;

  int tid = threadIdx.x;
  int wv = tid >> 6, ln = tid & 63;
  int q = ln >> 4, c = ln & 15;
  int wr = wv >> 1, wc = wv & 1;
  int mBase = mT * 128, nBase = nT * 128;

  f32x4 acc[4][4];
#pragma unroll
  for (int i = 0; i < 4; i++)
#pragma unroll
    for (int j = 0; j < 4; j++) acc[i][j] = (f32x4){0.f, 0.f, 0.f, 0.f};

  const u16* Ag = Ab + (size_t)mBase * lda;
  const u16*  Wg16 = (const u16*)Wv + (size_t)split * splitK + (size_t)nBase * ldw;
  const float* Wg32 = (const float*)Wv + (size_t)split * splitK + (size_t)nBase * ldw;

  for (int k0 = 0; k0 < K; k0 += 64) {
    // ---- stage 16KB A-tile + 16KB W-tile (16 chunks each, 4/wave) ----
#pragma unroll
    for (int i = 0; i < 4; i++) {
      int ch = wv * 4 + i;             // chunk 0..15 (1024B each)
      int s = ch >> 1;                 // k-slot (8 bf16), 0..7
      int r = (ch & 1) * 64 + ln;      // tile row
      GLDS16(Ag + (size_t)r * lda + (k0 + s * 8), &As[ch * 512]);
      if constexpr (MODE == 4) {
        const float* wp = Wg32 + (size_t)r * ldw + (k0 + s * 8);
        float4 f0 = *(const float4*)wp, f1 = *(const float4*)(wp + 4);
        short8 pk;
        pk[0] = (short)f2bf(f0.x); pk[1] = (short)f2bf(f0.y);
        pk[2] = (short)f2bf(f0.z); pk[3] = (short)f2bf(f0.w);
        pk[4] = (short)f2bf(f1.x); pk[5] = (short)f2bf(f1.y);
        pk[6] = (short)f2bf(f1.z); pk[7] = (short)f2bf(f1.w);
        *(short8*)&Bs[ch * 512 + ln * 8] = pk;
      } else {
        GLDS16(Wg16 + (size_t)r * ldw + (k0 + s * 8), &Bs[ch * 512]);
      }
    }
    __syncthreads();
#pragma unroll
    for (int kk = 0; kk < 2; kk++) {
      short8 afr[4], bfr[4];
#pragma unroll
      for (int mt2 = 0; mt2 < 4; mt2++)
        afr[mt2] = *(const short8*)&As[(((kk * 4 + q) * 128) + wr * 64 + mt2 * 16 + c) * 8];
#pragma unroll
      for (int nt2 = 0; nt2 < 4; nt2++)
        bfr[nt2] = *(const short8*)&Bs[(((kk * 4 + q) * 128) + wc * 64 + nt2 * 16 + c) * 8];
#pragma unroll
      for (int mt2 = 0; mt2 < 4; mt2++)
#pragma unroll
        for (int nt2 = 0; nt2 < 4; nt2++)
          acc[mt2][nt2] = __builtin_amdgcn_mfma_f32_16x16x32_bf16(
              afr[mt2], bfr[nt2], acc[mt2][nt2], 0, 0, 0);
    }
    __syncthreads();
  }

  // ---- epilogue ----
#pragma unroll
  for (int mt2 = 0; mt2 < 4; mt2++) {
    int row0 = mBase + wr * 64 + mt2 * 16 + q * 4;
#pragma unroll
    for (int nt2 = 0; nt2 < 4; nt2++) {
      int col = nBase + wc * 64 + nt2 * 16 + c;
      float bv = (MODE == 0 || MODE == 1 || MODE == 3) ? bias[col] : 0.f;
      f32x4 v = acc[mt2][nt2];
#pragma unroll
      for (int e = 0; e < 4; e++) {
        int row = row0 + e;
        float x = v[e] + bv;
        if (MODE == 0) x = fminf(fmaxf(x, 0.f), 6.f);
        if (MODE == 3) x += res[(size_t)row * N + col];
        if (MODE == 0 || MODE == 2) outU[(size_t)row * N + col] = f2bf(x);
        else                        outF[(size_t)row * N + col] = x;
      }
    }
  }
}

// ---------------------------------------------------------------------------
// x (B, CIN, HW, HW) f32  ->  A_t (B*NPOS, CIN) bf16
// ---------------------------------------------------------------------------
__global__ __launch_bounds__(256) void transpose_cast_k(
    const float* __restrict__ x, u16* __restrict__ At)
{
  __shared__ float t[32][33];
  int c0 = blockIdx.x * 32, n0 = blockIdx.y * 32, b = blockIdx.z;
  int tx = threadIdx.x, ty = threadIdx.y;
  const float* xb = x + (size_t)b * CIN * NPOS;
#pragma unroll
  for (int i = 0; i < 4; i++) {
    int cc = c0 + ty + i * 8, nn = n0 + tx;
    t[ty + i * 8][tx] = (nn < NPOS) ? xb[(size_t)cc * NPOS + nn] : 0.f;
  }
  __syncthreads();
  u16* Ab = At + (size_t)b * NPOS * CIN;
#pragma unroll
  for (int i = 0; i < 4; i++) {
    int nn = n0 + ty + i * 8, cc = c0 + tx;
    if (nn < NPOS) Ab[(size_t)nn * CIN + cc] = f2bf(t[tx][ty + i * 8]);
  }
}

// ---------------------------------------------------------------------------
// depthwise 3x3 SAME conv + bias + identity residual (fp32)
// ---------------------------------------------------------------------------
__global__ __launch_bounds__(256) void conv_res_k(
    const float* __restrict__ T0, const float* __restrict__ pcw,
    const float* __restrict__ pcb, float* __restrict__ T1)
{
  int idx = blockIdx.x * 256 + threadIdx.x;
  if (idx >= B_ * NPOS * 96) return;
  int d4 = idx % 96; int rem = idx / 96;
  int n = rem % NPOS; int b = rem / NPOS;
  int hh = n / 14, ww = n % 14;
  int d0 = d4 * 4;
  float w9[4][9];
#pragma unroll
  for (int j = 0; j < 4; j++)
#pragma unroll
    for (int t = 0; t < 9; t++) w9[j][t] = pcw[(d0 + j) * 9 + t];
  const float* base = T0 + (size_t)b * NPOS * DM;
  float4 ctr = *(const float4*)(base + (size_t)n * DM + d0);
  float ax = ctr.x + pcb[d0], ay = ctr.y + pcb[d0 + 1];
  float az = ctr.z + pcb[d0 + 2], aw = ctr.w + pcb[d0 + 3];
#pragma unroll
  for (int kh = 0; kh < 3; kh++) {
    int h2 = hh + kh - 1;
    if (h2 < 0 || h2 >= 14) continue;
#pragma unroll
    for (int kw = 0; kw < 3; kw++) {
      int w2 = ww + kw - 1;
      if (w2 < 0 || w2 >= 14) continue;
      float4 v = *(const float4*)(base + (size_t)(h2 * 14 + w2) * DM + d0);
      int t = kh * 3 + kw;
      ax += v.x * w9[0][t]; ay += v.y * w9[1][t];
      az += v.z * w9[2][t]; aw += v.w * w9[3][t];
    }
  }
  float4 o = {ax, ay, az, aw};
  *(float4*)(T1 + (size_t)b * NPOS * DM + (size_t)n * DM + d0) = o;
}

// ---------------------------------------------------------------------------
// LayerNorm(384) f32 -> bf16, one wave per row (float2-vectorized)
// ---------------------------------------------------------------------------
__global__ __launch_bounds__(256) void ln_k(
    const float* __restrict__ in, const float* __restrict__ w,
    const float* __restrict__ bb, u16* __restrict__ out)
{
  int row = blockIdx.x * 4 + (threadIdx.x >> 6);
  int ln = threadIdx.x & 63;
  const float2* r = (const float2*)(in + (size_t)row * DM);
  float2 v[3]; float s = 0.f, sq = 0.f;
#pragma unroll
  for (int j = 0; j < 3; j++) {
    v[j] = r[ln + 64 * j];
    s += v[j].x + v[j].y; sq += v[j].x * v[j].x + v[j].y * v[j].y;
  }
#pragma unroll
  for (int o = 1; o < 64; o <<= 1) { s += __shfl_xor(s, o, 64); sq += __shfl_xor(sq, o, 64); }
  float mu = s * (1.f / 384.f);
  float var = sq * (1.f / 384.f) - mu * mu;
  float rs = rsqrtf(var + 1e-5f);
  uint32_t* orow = (uint32_t*)(out + (size_t)row * DM);
#pragma unroll
  for (int j = 0; j < 3; j++) {
    int d = (ln + 64 * j) * 2;
    float a = (v[j].x - mu) * rs * w[d] + bb[d];
    float bq = (v[j].y - mu) * rs * w[d + 1] + bb[d + 1];
    orow[ln + 64 * j] = (uint32_t)f2bf(a) | ((uint32_t)f2bf(bq) << 16);
  }
}

// ---------------------------------------------------------------------------
// rpe_scores[b,h,i,t] = SCALE_Q * sum_d q[b,h,i,d] * table[d,t]   (fp32)
// ---------------------------------------------------------------------------
__global__ __launch_bounds__(256) void rpe_k(
    const u16* __restrict__ QKV, const float* __restrict__ tabG,
    float* __restrict__ Rb)
{
  __shared__ float qs[NPOS * 32];
  __shared__ float tab[32 * 49];
  int bh = blockIdx.x; int b = bh / NH_, h = bh % NH_;
  int tid = threadIdx.x;
  size_t qoff = (size_t)b * NPOS * 1152 + h * 32;
  for (int idx = tid; idx < NPOS * 32; idx += 256) {
    int n = idx >> 5, d = idx & 31;
    qs[idx] = bf2f(QKV[qoff + (size_t)n * 1152 + d]);
  }
  for (int idx = tid; idx < 32 * 49; idx += 256) tab[idx] = tabG[idx];
  __syncthreads();
  for (int idx = tid; idx < NPOS * 49; idx += 256) {
    int i = idx / 49, t = idx - i * 49;
    float s = 0.f;
#pragma unroll
    for (int d = 0; d < 32; d++) s += qs[i * 32 + d] * tab[d * 49 + t];
    Rb[(size_t)bh * 9604 + idx] = s * SCALE_Q;
  }
}

// ---------------------------------------------------------------------------
// Fused attention per (b,h).
//   Q,K fragments straight from global (L2-resident).
//   V^T staged in Vt[32][232] (zero-padded cols 196..231).
//   Per-wave, per-m-tile: bias rows Rbb[mb..mb+16) staged COALESCED into
//   Rbw (f32), then the 52/lane bias reads are LDS gathers (ds_read_b32)
//   instead of scattered global loads.
//   P strips in fragment layout Psf[26][16][8] per wave + shared zero pad.
// LDS = 14848 + 26624 + 12800 + 256 = 54528 B -> 3 blocks/CU.
// ---------------------------------------------------------------------------
__global__ __launch_bounds__(256) void attn_k(
    const u16* __restrict__ QKV, const float* __restrict__ Rb,
    u16* __restrict__ AO)
{
  __shared__ __align__(16) u16 Vt[32 * 232];       // [d][j], pad j>=196 zero
  __shared__ __align__(16) u16 Psf[4][26 * 16 * 8];// per-wave [slot][i][e]
  __shared__ __align__(16) float Rbw[4][16 * 50];  // per-wave bias rows
  __shared__ __align__(16) u16 Pz[128];            // 16 lanes x 8 zeros
  int bh = blockIdx.x; int b = bh / NH_, h = bh % NH_;
  int tid = threadIdx.x;
  int wv = tid >> 6, ln = tid & 63;
  int q = ln >> 4, c = ln & 15;
  size_t rowbase = (size_t)b * NPOS * 1152 + h * 32;

  // ---- stage V transposed (vectorized): 784 chunks of 8 d-values ----
  for (int t = tid; t < 784; t += 256) {
    int nn = t >> 2, d0 = (t & 3) * 8;
    short8 v = *(const short8*)(QKV + rowbase + 768 + (size_t)nn * 1152 + d0);
#pragma unroll
    for (int j = 0; j < 8; j++) Vt[(d0 + j) * 232 + nn] = (u16)v[j];
  }
  for (int t = tid; t < 32 * 36; t += 256) {
    int d = t / 36, jj = t - d * 36;
    Vt[d * 232 + 196 + jj] = 0;
  }
  if (tid < 64) ((u16*)Pz)[tid * 2] = 0, ((u16*)Pz)[tid * 2 + 1] = 0;
  __syncthreads();

  const float* Rbb = Rb + (size_t)bh * 9604;
  u16* Pw = Psf[wv];
  float* Rw = Rbw[wv];

  for (int mt = wv; mt < 13; mt += 4) {
    int mb = mt * 16;

    // ---- stage this wave's 16 bias rows, coalesced (784 f32) ----
    for (int t = ln; t < 784; t += 64) {
      int r = t / 49, t2 = t - r * 49;
      int src = mb + r; if (src > 195) src = 195;
      Rw[r * 50 + t2] = Rbb[src * 49 + t2];
    }

    int irow = mb + c; if (irow > 195) irow = 195;
    short8 afrag = *(const short8*)(QKV + rowbase + (size_t)irow * 1152 + q * 8);
    int i0 = mb + q * 4;

    f32x4 sacc[13];
#pragma unroll
    for (int nt = 0; nt < 13; nt++) {
      int jc = nt * 16 + c; if (jc > 195) jc = 195;
      short8 bfrag = *(const short8*)(QKV + rowbase + 384 + (size_t)jc * 1152 + q * 8);
      f32x4 z = {0.f, 0.f, 0.f, 0.f};
      sacc[nt] = __builtin_amdgcn_mfma_f32_16x16x32_bf16(afrag, bfrag, z, 0, 0, 0);
    }

    // scale + bucket bias (LDS gather) + mask
    int ri4[4], ci4[4];
#pragma unroll
    for (int e = 0; e < 4; e++) {
      int i = i0 + e; int ri = i / 14;
      ri4[e] = ri; ci4[e] = i - ri * 14;
    }
#pragma unroll
    for (int nt = 0; nt < 13; nt++) {
      int j = nt * 16 + c;
      int rj = j / 14, cj = j - rj * 14;
      bool jok = (j < 196);
#pragma unroll
      for (int e = 0; e < 4; e++) {
        int i = i0 + e;
        float sv = -1e30f;
        if (jok && i < 196) {
          int dr = ri4[e] - rj, dc = ci4[e] - cj;
          int adr = dr < 0 ? -dr : dr, adc = dc < 0 ? -dc : dc;
          int tr = adr <= 1 ? adr : (adr <= 3 ? 2 : 3);
          int tc = adc <= 1 ? adc : (adc <= 3 ? 2 : 3);
          int fr = dr < 0 ? -tr : tr, fc = dc < 0 ? -tc : tc;
          int bucket = fr * 7 + fc + 24;
          sv = sacc[nt][e] * SCALE_Q + Rw[(q * 4 + e) * 50 + bucket];
        }
        sacc[nt][e] = sv;
      }
    }

    // softmax (rows live in 16-lane groups)
    float mx[4], sm[4], inv[4];
#pragma unroll
    for (int e = 0; e < 4; e++) {
      float m = sacc[0][e];
#pragma unroll
      for (int nt = 1; nt < 13; nt++) m = fmaxf(m, sacc[nt][e]);
#pragma unroll
      for (int o = 1; o < 16; o <<= 1) m = fmaxf(m, __shfl_xor(m, o, 64));
      mx[e] = m; sm[e] = 0.f;
    }
#pragma unroll
    for (int nt = 0; nt < 13; nt++) {
#pragma unroll
      for (int e = 0; e < 4; e++) {
        float p = __expf(sacc[nt][e] - mx[e]);
        sm[e] += p;
        Pw[(nt * 2 + (c >> 3)) * 128 + (q * 4 + e) * 8 + (c & 7)] = f2bf(p);
      }
    }
#pragma unroll
    for (int e = 0; e < 4; e++) {
      float s2 = sm[e];
#pragma unroll
      for (int o = 1; o < 16; o <<= 1) s2 += __shfl_xor(s2, o, 64);
      inv[e] = 1.f / s2;
    }

    // P x V  (A-frag from Psf; k-tail slots 26,27 read shared zeros)
#pragma unroll
    for (int n2 = 0; n2 < 2; n2++) {
      f32x4 oacc = {0.f, 0.f, 0.f, 0.f};
#pragma unroll
      for (int kt = 0; kt < 7; kt++) {
        int ps = kt * 4 + q;
        const u16* pap = (ps < 26) ? &Pw[ps * 128 + c * 8] : &Pz[c * 8];
        short8 pa = *(const short8*)pap;
        short8 vb = *(const short8*)&Vt[(n2 * 16 + c) * 232 + kt * 32 + q * 8];
        oacc = __builtin_amdgcn_mfma_f32_16x16x32_bf16(pa, vb, oacc, 0, 0, 0);
      }
#pragma unroll
      for (int e = 0; e < 4; e++) {
        int i = i0 + e;
        if (i < 196) {
          int d = n2 * 16 + c;
          AO[((size_t)b * NPOS + i) * DM + h * 32 + d] = f2bf(oacc[e] * inv[e]);
        }
      }
    }
  }
}

// ---------------------------------------------------------------------------
// BN1 over (batch, dmodel) per position n: two-stage stats
// ---------------------------------------------------------------------------
__global__ __launch_bounds__(256) void bn1_partial_k(
    const float* __restrict__ T3, float* __restrict__ part)
{
  int n = blockIdx.x >> 3, g = blockIdx.x & 7;
  int tid = threadIdx.x;
  float s = 0.f, sq = 0.f;
  for (int b2 = g * 16; b2 < g * 16 + 16; b2++) {
    const float* p = T3 + ((size_t)b2 * NPOS + n) * DM;
    for (int d = tid; d < DM; d += 256) { float v = p[d]; s += v; sq += v * v; }
  }
#pragma unroll
  for (int o = 1; o < 64; o <<= 1) { s += __shfl_xor(s, o, 64); sq += __shfl_xor(sq, o, 64); }
  __shared__ float ls[4], lq[4];
  int wv = tid >> 6, ln = tid & 63;
  if (ln == 0) { ls[wv] = s; lq[wv] = sq; }
  __syncthreads();
  if (tid == 0) {
    part[blockIdx.x * 2]     = ls[0] + ls[1] + ls[2] + ls[3];
    part[blockIdx.x * 2 + 1] = lq[0] + lq[1] + lq[2] + lq[3];
  }
}

__global__ __launch_bounds__(256) void bn1_finish_k(
    const float* __restrict__ part, const float* __restrict__ bw,
    const float* __restrict__ bbb, float* __restrict__ scaleArr,
    float* __restrict__ shiftArr)
{
  int n = threadIdx.x;
  if (n >= NPOS) return;
  float S = 0.f, Q = 0.f;
#pragma unroll
  for (int g = 0; g < 8; g++) { S += part[(n * 8 + g) * 2]; Q += part[(n * 8 + g) * 2 + 1]; }
  float mu = S / 49152.f;
  float var = Q / 49152.f - mu * mu;
  float rs = rsqrtf(var + 2e-5f);
  float sc = rs * bw[n];
  scaleArr[n] = sc;
  shiftArr[n] = bbb[n] - mu * sc;
}

__global__ __launch_bounds__(256) void bn1_apply_k(
    const float* __restrict__ T3, const float* __restrict__ scaleArr,
    const float* __restrict__ shiftArr, u16* __restrict__ outb)
{
  int idx = blockIdx.x * 256 + threadIdx.x;           // float4 index
  if (idx >= MT * DM / 4) return;
  int n = (idx / 96) % NPOS;
  float4 v = *(const float4*)(T3 + (size_t)idx * 4);
  float sc = scaleArr[n], sh = shiftArr[n];
  uint32_t p0 = (uint32_t)f2bf(v.x * sc + sh) | ((uint32_t)f2bf(v.y * sc + sh) << 16);
  uint32_t p1 = (uint32_t)f2bf(v.z * sc + sh) | ((uint32_t)f2bf(v.w * sc + sh) << 16);
  ((uint2*)outb)[idx] = make_uint2(p0, p1);
}

// ---------------------------------------------------------------------------
// split-K reduce for lin head + bias
// ---------------------------------------------------------------------------
__global__ __launch_bounds__(256) void lin_reduce_k(
    const float* __restrict__ part, const float* __restrict__ lb,
    float* __restrict__ y)
{
  int idx = blockIdx.x * 256 + threadIdx.x;
  if (idx >= 128 * DM) return;
  int col = idx % DM;
  float s = lb[col];
#pragma unroll
  for (int sp = 0; sp < 49; sp++) s += part[(size_t)sp * (128 * DM) + idx];
  y[idx] = s;
}

// ---------------------------------------------------------------------------
// BN2 over batch (128) per feature col, in-place on y
// ---------------------------------------------------------------------------
__global__ __launch_bounds__(64) void bn2_k(
    float* __restrict__ y, const float* __restrict__ w,
    const float* __restrict__ bb)
{
  int col = blockIdx.x; int ln = threadIdx.x;
  float v0 = y[(size_t)ln * DM + col];
  float v1 = y[(size_t)(ln + 64) * DM + col];
  float s = v0 + v1, sq = v0 * v0 + v1 * v1;
#pragma unroll
  for (int o = 1; o < 64; o <<= 1) { s += __shfl_xor(s, o, 64); sq += __shfl_xor(sq, o, 64); }
  float mu = s / 128.f;
  float var = sq / 128.f - mu * mu;
  float rs = rsqrtf(var + 2e-5f);
  float sc = rs * w[col], sh = bb[col] - mu * sc;
  y[(size_t)ln * DM + col] = v0 * sc + sh;
  y[(size_t)(ln + 64) * DM + col] = v1 * sc + sh;
}

// ---------------------------------------------------------------------------
// f32 -> bf16 cast (vectorized, grid-stride over float4)
// ---------------------------------------------------------------------------
__global__ __launch_bounds__(256) void castv_k(
    const float* __restrict__ s, u16* __restrict__ d, int n4)
{
  int idx = blockIdx.x * 256 + threadIdx.x;
  int stride = gridDim.x * 256;
  for (; idx < n4; idx += stride) {
    float4 v = *(const float4*)(s + (size_t)idx * 4);
    uint32_t p0 = (uint32_t)f2bf(v.x) | ((uint32_t)f2bf(v.y) << 16);
    uint32_t p1 = (uint32_t)f2bf(v.z) | ((uint32_t)f2bf(v.w) << 16);
    ((uint2*)d)[idx] = make_uint2(p0, p1);
  }
}

// ---------------------------------------------------------------------------
// Orchestration
// ---------------------------------------------------------------------------
extern "C" void kernel_launch(void* const* d_in, const int* in_sizes, int n_in,
                              void* d_out, int out_size, void* d_ws, size_t ws_size,
                              hipStream_t stream)
{
  (void)in_sizes; (void)n_in; (void)out_size;
  const float* x    = (const float*)d_in[0];
  const float* fc1w = (const float*)d_in[1];
  const float* fc1b = (const float*)d_in[2];
  const float* fc2w = (const float*)d_in[3];
  const float* fc2b = (const float*)d_in[4];
  const float* pcw  = (const float*)d_in[5];
  const float* pcb  = (const float*)d_in[6];
  const float* ln1w = (const float*)d_in[7];
  const float* ln1b = (const float*)d_in[8];
  const float* qkvw = (const float*)d_in[9];
  const float* rpet = (const float*)d_in[10];
  const float* projw= (const float*)d_in[11];
  const float* projb= (const float*)d_in[12];
  const float* ln2w = (const float*)d_in[13];
  const float* ln2b = (const float*)d_in[14];
  const float* m1w  = (const float*)d_in[15];
  const float* m1b  = (const float*)d_in[16];
  const float* m2w  = (const float*)d_in[17];
  const float* m2b  = (const float*)d_in[18];
  const float* bn1w = (const float*)d_in[19];
  const float* bn1b = (const float*)d_in[20];
  const float* linw = (const float*)d_in[21];
  const float* linb = (const float*)d_in[22];
  const float* bn2w = (const float*)d_in[23];
  const float* bn2b = (const float*)d_in[24];
  float* y = (float*)d_out;

  // -------- aliased workspace layout (regions share by liveness) ----------
  const size_t RA = 0;                      // At / Rb / MLP1
  const size_t RB = 77070336;               // U / QKV / T3nb
  const size_t RC = RB + 57802752;          // H / AO / H2
  const size_t RD = RC + 19267584;          // T0 / T2
  const size_t RE = RD + 38535168;          // T1 / T3
  const size_t RF = RE + 38535168;          // PART (lin split-K)
  const size_t RG = RF + 9633792;           // small bf16 weights
  const size_t RS = RG + 6422528;           // bn1 scale/shift + partials
  const size_t NEED = RS + 2048 + 16384;
  if (ws_size < NEED) return;

  char* ws = (char*)d_ws;
  u16*   At    = (u16*)(ws + RA);
  float* Rb    = (float*)(ws + RA);
  u16*   MLP1  = (u16*)(ws + RA);
  u16*   U     = (u16*)(ws + RB);
  u16*   QKV   = (u16*)(ws + RB);
  u16*   T3nb  = (u16*)(ws + RB);
  u16*   H     = (u16*)(ws + RC);
  u16*   AO    = (u16*)(ws + RC);
  u16*   H2    = (u16*)(ws + RC);
  float* T0    = (float*)(ws + RD);
  float* T2    = (float*)(ws + RD);
  float* T1    = (float*)(ws + RE);
  float* T3    = (float*)(ws + RE);
  float* PART  = (float*)(ws + RF);
  u16*   wb_fc1 = (u16*)(ws + RG);
  u16*   wb_fc2 = wb_fc1 + 1048576;
  u16*   wb_qkv = wb_fc2 + 393216;
  u16*   wb_proj= wb_qkv + 442368;
  u16*   wb_m1  = wb_proj + 147456;
  u16*   wb_m2  = wb_m1 + 589824;
  float* bnS   = (float*)(ws + RS);
  float* bnSh  = bnS + 196;
  float* bnP   = (float*)(ws + RS + 2048);

  // weight casts (f32 -> bf16)
  castv_k<<<256, 256, 0, stream>>>(fc1w, wb_fc1, 262144);
  castv_k<<<128, 256, 0, stream>>>(fc2w, wb_fc2, 98304);
  castv_k<<<128, 256, 0, stream>>>(qkvw, wb_qkv, 110592);
  castv_k<<< 64, 256, 0, stream>>>(projw, wb_proj, 36864);
  castv_k<<<160, 256, 0, stream>>>(m1w, wb_m1, 147456);
  castv_k<<<160, 256, 0, stream>>>(m2w, wb_m2, 147456);

  // x (B,CIN,N) -> At (B*N, CIN) bf16
  transpose_cast_k<<<dim3(32, 7, 128), dim3(32, 8), 0, stream>>>(x, At);

  // embed fc1: U = relu6(At @ fc1w^T + b)   [25088 x 1024]
  gemm_k<0><<<196 * 8, 256, 0, stream>>>(At, wb_fc1, fc1b, nullptr, U,
                                          MT, 1024, 1024, 1024, 1024, 8, 0);
  // embed fc2: T0 = U @ fc2w^T + b          [25088 x 384] f32
  gemm_k<1><<<196 * 3, 256, 0, stream>>>(U, wb_fc2, fc2b, nullptr, T0,
                                          MT, 384, 1024, 1024, 1024, 3, 0);
  // depthwise conv + bias + residual -> T1
  conv_res_k<<<(B_ * NPOS * 96 + 255) / 256, 256, 0, stream>>>(T0, pcw, pcb, T1);
  // LN1 -> H (bf16)
  ln_k<<<MT / 4, 256, 0, stream>>>(T1, ln1w, ln1b, H);
  // qkv: QKV = H @ qkvw^T (no bias)          [25088 x 1152] bf16
  gemm_k<2><<<196 * 9, 256, 0, stream>>>(H, wb_qkv, nullptr, nullptr, QKV,
                                          MT, 1152, 384, 384, 384, 9, 0);
  // rpe scores (scale folded)
  rpe_k<<<1536, 256, 0, stream>>>(QKV, rpet, Rb);
  // fused attention -> AO (bf16)
  attn_k<<<1536, 256, 0, stream>>>(QKV, Rb, AO);
  // proj + residual(T1) -> T2 (f32)
  gemm_k<3><<<196 * 3, 256, 0, stream>>>(AO, wb_proj, projb, T1, T2,
                                          MT, 384, 384, 384, 384, 3, 0);
  // LN2 -> H2 (bf16)
  ln_k<<<MT / 4, 256, 0, stream>>>(T2, ln2w, ln2b, H2);
  // mlp fc1: MLP1 = relu6(H2 @ m1w^T + b)    [25088 x 1536] bf16
  gemm_k<0><<<196 * 12, 256, 0, stream>>>(H2, wb_m1, m1b, nullptr, MLP1,
                                           MT, 1536, 384, 384, 384, 12, 0);
  // mlp fc2 + residual(T2) -> T3 (f32)
  gemm_k<3><<<196 * 3, 256, 0, stream>>>(MLP1, wb_m2, m2b, T2, T3,
                                          MT, 384, 1536, 1536, 1536, 3, 0);
  // BN1 (per position) -> T3nb (bf16)
  bn1_partial_k<<<196 * 8, 256, 0, stream>>>(T3, bnP);
  bn1_finish_k<<<1, 256, 0, stream>>>(bnP, bn1w, bn1b, bnS, bnSh);
  bn1_apply_k<<<(MT * DM / 4 + 255) / 256, 256, 0, stream>>>(T3, bnS, bnSh, T3nb);
  // lin head: y = T3nb(128 x 75264) @ linw^T, split-K 49 x 1536 (W f32 direct)
  gemm_k<4><<<3 * 49, 256, 0, stream>>>(T3nb, linw, nullptr, nullptr, PART,
                                         128, 384, 1536, 75264, 75264, 3, 1536);
  lin_reduce_k<<<192, 256, 0, stream>>>(PART, linb, y);
  // BN2 (per feature over batch), in place on d_out
  bn2_k<<<384, 64, 0, stream>>>(y, bn2w, bn2b);
}

// Round 4
// 892.445 us; speedup vs baseline: 1.1695x; 1.0324x over previous
//
#include <hip/hip_runtime.h>
#include <cstdint>

// ---------------------------------------------------------------------------
// Problem constants
// ---------------------------------------------------------------------------
#define B_    128
#define CIN   1024
#define NPOS  196          // 14*14
#define DM    384
#define NH_   12
#define HD_   32
#define DFF_  1536
#define MT    25088        // B_*NPOS
#define SCALE_Q 0.17677669529663687f   // 1/sqrt(32)

typedef unsigned short u16;
typedef __attribute__((ext_vector_type(8))) short  short8;   // 8 bf16 (4 VGPR)
typedef __attribute__((ext_vector_type(4))) float  f32x4;    // MFMA C/D

__device__ __forceinline__ u16 f2bf(float f) {
  union { float f; uint32_t u; } v; v.f = f;
  uint32_t u = v.u;
  return (u16)((u + 0x7fffu + ((u >> 16) & 1u)) >> 16);
}
__device__ __forceinline__ float bf2f(u16 h) {
  union { uint32_t u; float f; } v; v.u = ((uint32_t)h) << 16;
  return v.f;
}

#define GLDS16(g, l)                                                           \
  __builtin_amdgcn_global_load_lds(                                            \
      (const __attribute__((address_space(1))) void*)(g),                      \
      (__attribute__((address_space(3))) void*)(l), 16, 0, 0)

// ---------------------------------------------------------------------------
// Generic bf16 MFMA GEMM:  out = epi( A[M x K] * W[N x K]^T )
// 128x128 tile, 4 waves (2x2 of 64x64), BK=64, 32 MFMA / K-step.
// MODE: 0 = bias+relu6 -> bf16   (fc1, mlp1)
//       1 = bias       -> f32    (fc2)
//       2 = plain      -> bf16   (qkv)
//       3 = bias+res   -> f32    (proj, mlp2)
//       4 = split-K partial -> f32 (lin head; W is f32, converted in staging)
// ---------------------------------------------------------------------------
template <int MODE>
__global__ __launch_bounds__(256) void gemm_k(
    const u16* __restrict__ A, const void* __restrict__ Wv,
    const float* __restrict__ bias, const float* __restrict__ res,
    void* __restrict__ outp,
    int M, int N, int K, int lda, int ldw, int nTN, int splitK)
{
  __shared__ __align__(16) u16 As[8 * 128 * 8];   // [s][r][8], s = k-slot (8 bf16)
  __shared__ __align__(16) u16 Bs[8 * 128 * 8];

  int bid = blockIdx.x;
  int split = 0, mT, nT;
  if (MODE == 4) { split = bid / nTN; nT = bid % nTN; mT = 0; }
  else           { mT = bid / nTN;    nT = bid % nTN; }

  const u16* Ab = A + (size_t)split * splitK;
  float* outF = (float*)outp + ((MODE == 4) ? (size_t)split * (size_t)M * N : (size_t)0);
  u16*   outU = (u16*)outp;

  int tid = threadIdx.x;
  int wv = tid >> 6, ln = tid & 63;
  int q = ln >> 4, c = ln & 15;
  int wr = wv >> 1, wc = wv & 1;
  int mBase = mT * 128, nBase = nT * 128;

  f32x4 acc[4][4];
#pragma unroll
  for (int i = 0; i < 4; i++)
#pragma unroll
    for (int j = 0; j < 4; j++) acc[i][j] = (f32x4){0.f, 0.f, 0.f, 0.f};

  const u16* Ag = Ab + (size_t)mBase * lda;
  const u16*  Wg16 = (const u16*)Wv + (size_t)split * splitK + (size_t)nBase * ldw;
  const float* Wg32 = (const float*)Wv + (size_t)split * splitK + (size_t)nBase * ldw;

  for (int k0 = 0; k0 < K; k0 += 64) {
    // ---- stage 16KB A-tile + 16KB W-tile (16 chunks each, 4/wave) ----
#pragma unroll
    for (int i = 0; i < 4; i++) {
      int ch = wv * 4 + i;             // chunk 0..15 (1024B each)
      int s = ch >> 1;                 // k-slot (8 bf16), 0..7
      int r = (ch & 1) * 64 + ln;      // tile row
      GLDS16(Ag + (size_t)r * lda + (k0 + s * 8), &As[ch * 512]);
      if constexpr (MODE == 4) {
        const float* wp = Wg32 + (size_t)r * ldw + (k0 + s * 8);
        float4 f0 = *(const float4*)wp, f1 = *(const float4*)(wp + 4);
        short8 pk;
        pk[0] = (short)f2bf(f0.x); pk[1] = (short)f2bf(f0.y);
        pk[2] = (short)f2bf(f0.z); pk[3] = (short)f2bf(f0.w);
        pk[4] = (short)f2bf(f1.x); pk[5] = (short)f2bf(f1.y);
        pk[6] = (short)f2bf(f1.z); pk[7] = (short)f2bf(f1.w);
        *(short8*)&Bs[ch * 512 + ln * 8] = pk;
      } else {
        GLDS16(Wg16 + (size_t)r * ldw + (k0 + s * 8), &Bs[ch * 512]);
      }
    }
    __syncthreads();
#pragma unroll
    for (int kk = 0; kk < 2; kk++) {
      short8 afr[4], bfr[4];
#pragma unroll
      for (int mt2 = 0; mt2 < 4; mt2++)
        afr[mt2] = *(const short8*)&As[(((kk * 4 + q) * 128) + wr * 64 + mt2 * 16 + c) * 8];
#pragma unroll
      for (int nt2 = 0; nt2 < 4; nt2++)
        bfr[nt2] = *(const short8*)&Bs[(((kk * 4 + q) * 128) + wc * 64 + nt2 * 16 + c) * 8];
#pragma unroll
      for (int mt2 = 0; mt2 < 4; mt2++)
#pragma unroll
        for (int nt2 = 0; nt2 < 4; nt2++)
          acc[mt2][nt2] = __builtin_amdgcn_mfma_f32_16x16x32_bf16(
              afr[mt2], bfr[nt2], acc[mt2][nt2], 0, 0, 0);
    }
    __syncthreads();
  }

  // ---- epilogue ----
#pragma unroll
  for (int mt2 = 0; mt2 < 4; mt2++) {
    int row0 = mBase + wr * 64 + mt2 * 16 + q * 4;
#pragma unroll
    for (int nt2 = 0; nt2 < 4; nt2++) {
      int col = nBase + wc * 64 + nt2 * 16 + c;
      float bv = (MODE == 0 || MODE == 1 || MODE == 3) ? bias[col] : 0.f;
      f32x4 v = acc[mt2][nt2];
#pragma unroll
      for (int e = 0; e < 4; e++) {
        int row = row0 + e;
        float x = v[e] + bv;
        if (MODE == 0) x = fminf(fmaxf(x, 0.f), 6.f);
        if (MODE == 3) x += res[(size_t)row * N + col];
        if (MODE == 0 || MODE == 2) outU[(size_t)row * N + col] = f2bf(x);
        else                        outF[(size_t)row * N + col] = x;
      }
    }
  }
}

// ---------------------------------------------------------------------------
// x (B, CIN, HW, HW) f32  ->  A_t (B*NPOS, CIN) bf16
// ---------------------------------------------------------------------------
__global__ __launch_bounds__(256) void transpose_cast_k(
    const float* __restrict__ x, u16* __restrict__ At)
{
  __shared__ float t[32][33];
  int c0 = blockIdx.x * 32, n0 = blockIdx.y * 32, b = blockIdx.z;
  int tx = threadIdx.x, ty = threadIdx.y;
  const float* xb = x + (size_t)b * CIN * NPOS;
#pragma unroll
  for (int i = 0; i < 4; i++) {
    int cc = c0 + ty + i * 8, nn = n0 + tx;
    t[ty + i * 8][tx] = (nn < NPOS) ? xb[(size_t)cc * NPOS + nn] : 0.f;
  }
  __syncthreads();
  u16* Ab = At + (size_t)b * NPOS * CIN;
#pragma unroll
  for (int i = 0; i < 4; i++) {
    int nn = n0 + ty + i * 8, cc = c0 + tx;
    if (nn < NPOS) Ab[(size_t)nn * CIN + cc] = f2bf(t[tx][ty + i * 8]);
  }
}

// ---------------------------------------------------------------------------
// depthwise 3x3 SAME conv + bias + identity residual (fp32)
// ---------------------------------------------------------------------------
__global__ __launch_bounds__(256) void conv_res_k(
    const float* __restrict__ T0, const float* __restrict__ pcw,
    const float* __restrict__ pcb, float* __restrict__ T1)
{
  int idx = blockIdx.x * 256 + threadIdx.x;
  if (idx >= B_ * NPOS * 96) return;
  int d4 = idx % 96; int rem = idx / 96;
  int n = rem % NPOS; int b = rem / NPOS;
  int hh = n / 14, ww = n % 14;
  int d0 = d4 * 4;
  float w9[4][9];
#pragma unroll
  for (int j = 0; j < 4; j++)
#pragma unroll
    for (int t = 0; t < 9; t++) w9[j][t] = pcw[(d0 + j) * 9 + t];
  const float* base = T0 + (size_t)b * NPOS * DM;
  float4 ctr = *(const float4*)(base + (size_t)n * DM + d0);
  float ax = ctr.x + pcb[d0], ay = ctr.y + pcb[d0 + 1];
  float az = ctr.z + pcb[d0 + 2], aw = ctr.w + pcb[d0 + 3];
#pragma unroll
  for (int kh = 0; kh < 3; kh++) {
    int h2 = hh + kh - 1;
    if (h2 < 0 || h2 >= 14) continue;
#pragma unroll
    for (int kw = 0; kw < 3; kw++) {
      int w2 = ww + kw - 1;
      if (w2 < 0 || w2 >= 14) continue;
      float4 v = *(const float4*)(base + (size_t)(h2 * 14 + w2) * DM + d0);
      int t = kh * 3 + kw;
      ax += v.x * w9[0][t]; ay += v.y * w9[1][t];
      az += v.z * w9[2][t]; aw += v.w * w9[3][t];
    }
  }
  float4 o = {ax, ay, az, aw};
  *(float4*)(T1 + (size_t)b * NPOS * DM + (size_t)n * DM + d0) = o;
}

// ---------------------------------------------------------------------------
// LayerNorm(384) f32 -> bf16, one wave per row (float2-vectorized)
// ---------------------------------------------------------------------------
__global__ __launch_bounds__(256) void ln_k(
    const float* __restrict__ in, const float* __restrict__ w,
    const float* __restrict__ bb, u16* __restrict__ out)
{
  int row = blockIdx.x * 4 + (threadIdx.x >> 6);
  int ln = threadIdx.x & 63;
  const float2* r = (const float2*)(in + (size_t)row * DM);
  float2 v[3]; float s = 0.f, sq = 0.f;
#pragma unroll
  for (int j = 0; j < 3; j++) {
    v[j] = r[ln + 64 * j];
    s += v[j].x + v[j].y; sq += v[j].x * v[j].x + v[j].y * v[j].y;
  }
#pragma unroll
  for (int o = 1; o < 64; o <<= 1) { s += __shfl_xor(s, o, 64); sq += __shfl_xor(sq, o, 64); }
  float mu = s * (1.f / 384.f);
  float var = sq * (1.f / 384.f) - mu * mu;
  float rs = rsqrtf(var + 1e-5f);
  uint32_t* orow = (uint32_t*)(out + (size_t)row * DM);
#pragma unroll
  for (int j = 0; j < 3; j++) {
    int d = (ln + 64 * j) * 2;
    float a = (v[j].x - mu) * rs * w[d] + bb[d];
    float bq = (v[j].y - mu) * rs * w[d + 1] + bb[d + 1];
    orow[ln + 64 * j] = (uint32_t)f2bf(a) | ((uint32_t)f2bf(bq) << 16);
  }
}

// ---------------------------------------------------------------------------
// Fused attention per (b,h).  rpe_scores computed IN-KERNEL via MFMA:
//   scores(16x49) = Q_tile(16x32) x rpe_table(32x49), reusing the QK A-frag;
//   table B-fragments live in 16 VGPRs (loaded once per block).
//   Q,K fragments straight from global (L2/L3-resident).
//   V^T staged in Vt[32][232]; P strips in Psf[26][16][8] per wave.
// LDS = 14848 + 26624 + 12544 + 256 = 54272 B -> 3 blocks/CU.
// ---------------------------------------------------------------------------
__global__ __launch_bounds__(256) void attn_k(
    const u16* __restrict__ QKV, const float* __restrict__ tabG,
    u16* __restrict__ AO)
{
  __shared__ __align__(16) u16 Vt[32 * 232];        // [d][j], pad j>=196 zero
  __shared__ __align__(16) u16 Psf[4][26 * 16 * 8]; // per-wave [slot][i][e]
  __shared__ __align__(16) float Rw4[4][16 * 49];   // per-wave rpe scores
  __shared__ __align__(16) u16 Pz[128];             // 16 lanes x 8 zeros
  int bh = blockIdx.x; int b = bh / NH_, h = bh % NH_;
  int tid = threadIdx.x;
  int wv = tid >> 6, ln = tid & 63;
  int q = ln >> 4, c = ln & 15;
  size_t rowbase = (size_t)b * NPOS * 1152 + h * 32;

  // ---- rpe_table B-fragments in registers: tb[nt][jj] = tab[d=q*8+jj][t=nt*16+c]
  short8 tb[4];
#pragma unroll
  for (int nt = 0; nt < 4; nt++) {
    int t = nt * 16 + c;
#pragma unroll
    for (int jj = 0; jj < 8; jj++) {
      float v = (t < 49) ? tabG[(q * 8 + jj) * 49 + t] : 0.f;
      tb[nt][jj] = (short)f2bf(v);
    }
  }

  // ---- stage V transposed (vectorized): 784 chunks of 8 d-values ----
  for (int t = tid; t < 784; t += 256) {
    int nn = t >> 2, d0 = (t & 3) * 8;
    short8 v = *(const short8*)(QKV + rowbase + 768 + (size_t)nn * 1152 + d0);
#pragma unroll
    for (int j = 0; j < 8; j++) Vt[(d0 + j) * 232 + nn] = (u16)v[j];
  }
  for (int t = tid; t < 32 * 36; t += 256) {
    int d = t / 36, jj = t - d * 36;
    Vt[d * 232 + 196 + jj] = 0;
  }
  if (tid < 64) ((u16*)Pz)[tid * 2] = 0, ((u16*)Pz)[tid * 2 + 1] = 0;
  __syncthreads();

  u16* Pw = Psf[wv];
  float* Rw = Rw4[wv];

  for (int mt = wv; mt < 13; mt += 4) {
    int mb = mt * 16;
    int irow = mb + c; if (irow > 195) irow = 195;
    short8 afrag = *(const short8*)(QKV + rowbase + (size_t)irow * 1152 + q * 8);
    int i0 = mb + q * 4;

    // ---- rpe scores via MFMA -> Rw (same A-frag as QK^T) ----
#pragma unroll
    for (int nt = 0; nt < 4; nt++) {
      f32x4 z = {0.f, 0.f, 0.f, 0.f};
      f32x4 rr = __builtin_amdgcn_mfma_f32_16x16x32_bf16(afrag, tb[nt], z, 0, 0, 0);
      int t = nt * 16 + c;
      if (t < 49) {
#pragma unroll
        for (int e = 0; e < 4; e++)
          Rw[(q * 4 + e) * 49 + t] = rr[e] * SCALE_Q;
      }
    }

    // ---- QK^T ----
    f32x4 sacc[13];
#pragma unroll
    for (int nt = 0; nt < 13; nt++) {
      int jc = nt * 16 + c; if (jc > 195) jc = 195;
      short8 bfrag = *(const short8*)(QKV + rowbase + 384 + (size_t)jc * 1152 + q * 8);
      f32x4 z = {0.f, 0.f, 0.f, 0.f};
      sacc[nt] = __builtin_amdgcn_mfma_f32_16x16x32_bf16(afrag, bfrag, z, 0, 0, 0);
    }

    // ---- scale + bucket bias (LDS gather) + mask ----
    int ri4[4], ci4[4];
#pragma unroll
    for (int e = 0; e < 4; e++) {
      int i = i0 + e; int ri = i / 14;
      ri4[e] = ri; ci4[e] = i - ri * 14;
    }
#pragma unroll
    for (int nt = 0; nt < 13; nt++) {
      int j = nt * 16 + c;
      int rj = j / 14, cj = j - rj * 14;
      bool jok = (j < 196);
#pragma unroll
      for (int e = 0; e < 4; e++) {
        int i = i0 + e;
        float sv = -1e30f;
        if (jok && i < 196) {
          int dr = ri4[e] - rj, dc = ci4[e] - cj;
          int adr = dr < 0 ? -dr : dr, adc = dc < 0 ? -dc : dc;
          int tr = adr <= 1 ? adr : (adr <= 3 ? 2 : 3);
          int tc = adc <= 1 ? adc : (adc <= 3 ? 2 : 3);
          int fr = dr < 0 ? -tr : tr, fc = dc < 0 ? -tc : tc;
          int bucket = fr * 7 + fc + 24;
          sv = sacc[nt][e] * SCALE_Q + Rw[(q * 4 + e) * 49 + bucket];
        }
        sacc[nt][e] = sv;
      }
    }

    // ---- softmax (rows live in 16-lane groups) ----
    float mx[4], sm[4], inv[4];
#pragma unroll
    for (int e = 0; e < 4; e++) {
      float m = sacc[0][e];
#pragma unroll
      for (int nt = 1; nt < 13; nt++) m = fmaxf(m, sacc[nt][e]);
#pragma unroll
      for (int o = 1; o < 16; o <<= 1) m = fmaxf(m, __shfl_xor(m, o, 64));
      mx[e] = m; sm[e] = 0.f;
    }
#pragma unroll
    for (int nt = 0; nt < 13; nt++) {
#pragma unroll
      for (int e = 0; e < 4; e++) {
        float p = __expf(sacc[nt][e] - mx[e]);
        sm[e] += p;
        Pw[(nt * 2 + (c >> 3)) * 128 + (q * 4 + e) * 8 + (c & 7)] = f2bf(p);
      }
    }
#pragma unroll
    for (int e = 0; e < 4; e++) {
      float s2 = sm[e];
#pragma unroll
      for (int o = 1; o < 16; o <<= 1) s2 += __shfl_xor(s2, o, 64);
      inv[e] = 1.f / s2;
    }

    // ---- P x V ----
#pragma unroll
    for (int n2 = 0; n2 < 2; n2++) {
      f32x4 oacc = {0.f, 0.f, 0.f, 0.f};
#pragma unroll
      for (int kt = 0; kt < 7; kt++) {
        int ps = kt * 4 + q;
        const u16* pap = (ps < 26) ? &Pw[ps * 128 + c * 8] : &Pz[c * 8];
        short8 pa = *(const short8*)pap;
        short8 vb = *(const short8*)&Vt[(n2 * 16 + c) * 232 + kt * 32 + q * 8];
        oacc = __builtin_amdgcn_mfma_f32_16x16x32_bf16(pa, vb, oacc, 0, 0, 0);
      }
#pragma unroll
      for (int e = 0; e < 4; e++) {
        int i = i0 + e;
        if (i < 196) {
          int d = n2 * 16 + c;
          AO[((size_t)b * NPOS + i) * DM + h * 32 + d] = f2bf(oacc[e] * inv[e]);
        }
      }
    }
  }
}

// ---------------------------------------------------------------------------
// BN1 over (batch, dmodel) per position n: two-stage stats
// ---------------------------------------------------------------------------
__global__ __launch_bounds__(256) void bn1_partial_k(
    const float* __restrict__ T3, float* __restrict__ part)
{
  int n = blockIdx.x >> 3, g = blockIdx.x & 7;
  int tid = threadIdx.x;
  float s = 0.f, sq = 0.f;
  for (int b2 = g * 16; b2 < g * 16 + 16; b2++) {
    const float* p = T3 + ((size_t)b2 * NPOS + n) * DM;
    for (int d = tid; d < DM; d += 256) { float v = p[d]; s += v; sq += v * v; }
  }
#pragma unroll
  for (int o = 1; o < 64; o <<= 1) { s += __shfl_xor(s, o, 64); sq += __shfl_xor(sq, o, 64); }
  __shared__ float ls[4], lq[4];
  int wv = tid >> 6, ln = tid & 63;
  if (ln == 0) { ls[wv] = s; lq[wv] = sq; }
  __syncthreads();
  if (tid == 0) {
    part[blockIdx.x * 2]     = ls[0] + ls[1] + ls[2] + ls[3];
    part[blockIdx.x * 2 + 1] = lq[0] + lq[1] + lq[2] + lq[3];
  }
}

__global__ __launch_bounds__(256) void bn1_finish_k(
    const float* __restrict__ part, const float* __restrict__ bw,
    const float* __restrict__ bbb, float* __restrict__ scaleArr,
    float* __restrict__ shiftArr)
{
  int n = threadIdx.x;
  if (n >= NPOS) return;
  float S = 0.f, Q = 0.f;
#pragma unroll
  for (int g = 0; g < 8; g++) { S += part[(n * 8 + g) * 2]; Q += part[(n * 8 + g) * 2 + 1]; }
  float mu = S / 49152.f;
  float var = Q / 49152.f - mu * mu;
  float rs = rsqrtf(var + 2e-5f);
  float sc = rs * bw[n];
  scaleArr[n] = sc;
  shiftArr[n] = bbb[n] - mu * sc;
}

__global__ __launch_bounds__(256) void bn1_apply_k(
    const float* __restrict__ T3, const float* __restrict__ scaleArr,
    const float* __restrict__ shiftArr, u16* __restrict__ outb)
{
  int idx = blockIdx.x * 256 + threadIdx.x;           // float4 index
  if (idx >= MT * DM / 4) return;
  int n = (idx / 96) % NPOS;
  float4 v = *(const float4*)(T3 + (size_t)idx * 4);
  float sc = scaleArr[n], sh = shiftArr[n];
  uint32_t p0 = (uint32_t)f2bf(v.x * sc + sh) | ((uint32_t)f2bf(v.y * sc + sh) << 16);
  uint32_t p1 = (uint32_t)f2bf(v.z * sc + sh) | ((uint32_t)f2bf(v.w * sc + sh) << 16);
  ((uint2*)outb)[idx] = make_uint2(p0, p1);
}

// ---------------------------------------------------------------------------
// split-K reduce for lin head + bias
// ---------------------------------------------------------------------------
__global__ __launch_bounds__(256) void lin_reduce_k(
    const float* __restrict__ part, const float* __restrict__ lb,
    float* __restrict__ y)
{
  int idx = blockIdx.x * 256 + threadIdx.x;
  if (idx >= 128 * DM) return;
  int col = idx % DM;
  float s = lb[col];
#pragma unroll
  for (int sp = 0; sp < 49; sp++) s += part[(size_t)sp * (128 * DM) + idx];
  y[idx] = s;
}

// ---------------------------------------------------------------------------
// BN2 over batch (128) per feature col, in-place on y
// ---------------------------------------------------------------------------
__global__ __launch_bounds__(64) void bn2_k(
    float* __restrict__ y, const float* __restrict__ w,
    const float* __restrict__ bb)
{
  int col = blockIdx.x; int ln = threadIdx.x;
  float v0 = y[(size_t)ln * DM + col];
  float v1 = y[(size_t)(ln + 64) * DM + col];
  float s = v0 + v1, sq = v0 * v0 + v1 * v1;
#pragma unroll
  for (int o = 1; o < 64; o <<= 1) { s += __shfl_xor(s, o, 64); sq += __shfl_xor(sq, o, 64); }
  float mu = s / 128.f;
  float var = sq / 128.f - mu * mu;
  float rs = rsqrtf(var + 2e-5f);
  float sc = rs * w[col], sh = bb[col] - mu * sc;
  y[(size_t)ln * DM + col] = v0 * sc + sh;
  y[(size_t)(ln + 64) * DM + col] = v1 * sc + sh;
}

// ---------------------------------------------------------------------------
// merged f32 -> bf16 cast for the six small weight matrices
// segment boundaries in float4 units
// ---------------------------------------------------------------------------
__global__ __launch_bounds__(256) void castall_k(
    const float* __restrict__ s0, u16* __restrict__ d0,
    const float* __restrict__ s1, u16* __restrict__ d1,
    const float* __restrict__ s2, u16* __restrict__ d2,
    const float* __restrict__ s3, u16* __restrict__ d3,
    const float* __restrict__ s4, u16* __restrict__ d4,
    const float* __restrict__ s5, u16* __restrict__ d5)
{
  const int b0 = 262144, b1 = b0 + 98304, b2 = b1 + 110592,
            b3 = b2 + 36864, b4 = b3 + 147456, b5 = b4 + 147456; // 802816
  int idx = blockIdx.x * 256 + threadIdx.x;
  int stride = gridDim.x * 256;
  for (; idx < b5; idx += stride) {
    const float* s; u16* d; int l;
    if      (idx < b0) { s = s0; d = d0; l = idx; }
    else if (idx < b1) { s = s1; d = d1; l = idx - b0; }
    else if (idx < b2) { s = s2; d = d2; l = idx - b1; }
    else if (idx < b3) { s = s3; d = d3; l = idx - b2; }
    else if (idx < b4) { s = s4; d = d4; l = idx - b3; }
    else               { s = s5; d = d5; l = idx - b4; }
    float4 v = *(const float4*)(s + (size_t)l * 4);
    uint32_t p0 = (uint32_t)f2bf(v.x) | ((uint32_t)f2bf(v.y) << 16);
    uint32_t p1 = (uint32_t)f2bf(v.z) | ((uint32_t)f2bf(v.w) << 16);
    ((uint2*)d)[l] = make_uint2(p0, p1);
  }
}

// ---------------------------------------------------------------------------
// Orchestration
// ---------------------------------------------------------------------------
extern "C" void kernel_launch(void* const* d_in, const int* in_sizes, int n_in,
                              void* d_out, int out_size, void* d_ws, size_t ws_size,
                              hipStream_t stream)
{
  (void)in_sizes; (void)n_in; (void)out_size;
  const float* x    = (const float*)d_in[0];
  const float* fc1w = (const float*)d_in[1];
  const float* fc1b = (const float*)d_in[2];
  const float* fc2w = (const float*)d_in[3];
  const float* fc2b = (const float*)d_in[4];
  const float* pcw  = (const float*)d_in[5];
  const float* pcb  = (const float*)d_in[6];
  const float* ln1w = (const float*)d_in[7];
  const float* ln1b = (const float*)d_in[8];
  const float* qkvw = (const float*)d_in[9];
  const float* rpet = (const float*)d_in[10];
  const float* projw= (const float*)d_in[11];
  const float* projb= (const float*)d_in[12];
  const float* ln2w = (const float*)d_in[13];
  const float* ln2b = (const float*)d_in[14];
  const float* m1w  = (const float*)d_in[15];
  const float* m1b  = (const float*)d_in[16];
  const float* m2w  = (const float*)d_in[17];
  const float* m2b  = (const float*)d_in[18];
  const float* bn1w = (const float*)d_in[19];
  const float* bn1b = (const float*)d_in[20];
  const float* linw = (const float*)d_in[21];
  const float* linb = (const float*)d_in[22];
  const float* bn2w = (const float*)d_in[23];
  const float* bn2b = (const float*)d_in[24];
  float* y = (float*)d_out;

  // -------- aliased workspace layout (regions share by liveness) ----------
  const size_t RA = 0;                      // At / MLP1
  const size_t RB = 77070336;               // U / QKV / T3nb
  const size_t RC = RB + 57802752;          // H / AO / H2
  const size_t RD = RC + 19267584;          // T0 / T2
  const size_t RE = RD + 38535168;          // T1 / T3
  const size_t RF = RE + 38535168;          // PART (lin split-K)
  const size_t RG = RF + 9633792;           // small bf16 weights
  const size_t RS = RG + 6422528;           // bn1 scale/shift + partials
  const size_t NEED = RS + 2048 + 16384;
  if (ws_size < NEED) return;

  char* ws = (char*)d_ws;
  u16*   At    = (u16*)(ws + RA);
  u16*   MLP1  = (u16*)(ws + RA);
  u16*   U     = (u16*)(ws + RB);
  u16*   QKV   = (u16*)(ws + RB);
  u16*   T3nb  = (u16*)(ws + RB);
  u16*   H     = (u16*)(ws + RC);
  u16*   AO    = (u16*)(ws + RC);
  u16*   H2    = (u16*)(ws + RC);
  float* T0    = (float*)(ws + RD);
  float* T2    = (float*)(ws + RD);
  float* T1    = (float*)(ws + RE);
  float* T3    = (float*)(ws + RE);
  float* PART  = (float*)(ws + RF);
  u16*   wb_fc1 = (u16*)(ws + RG);
  u16*   wb_fc2 = wb_fc1 + 1048576;
  u16*   wb_qkv = wb_fc2 + 393216;
  u16*   wb_proj= wb_qkv + 442368;
  u16*   wb_m1  = wb_proj + 147456;
  u16*   wb_m2  = wb_m1 + 589824;
  float* bnS   = (float*)(ws + RS);
  float* bnSh  = bnS + 196;
  float* bnP   = (float*)(ws + RS + 2048);

  // weight casts (f32 -> bf16), one merged kernel
  castall_k<<<1024, 256, 0, stream>>>(fc1w, wb_fc1, fc2w, wb_fc2, qkvw, wb_qkv,
                                      projw, wb_proj, m1w, wb_m1, m2w, wb_m2);

  // x (B,CIN,N) -> At (B*N, CIN) bf16
  transpose_cast_k<<<dim3(32, 7, 128), dim3(32, 8), 0, stream>>>(x, At);

  // embed fc1: U = relu6(At @ fc1w^T + b)   [25088 x 1024]
  gemm_k<0><<<196 * 8, 256, 0, stream>>>(At, wb_fc1, fc1b, nullptr, U,
                                          MT, 1024, 1024, 1024, 1024, 8, 0);
  // embed fc2: T0 = U @ fc2w^T + b          [25088 x 384] f32
  gemm_k<1><<<196 * 3, 256, 0, stream>>>(U, wb_fc2, fc2b, nullptr, T0,
                                          MT, 384, 1024, 1024, 1024, 3, 0);
  // depthwise conv + bias + residual -> T1
  conv_res_k<<<(B_ * NPOS * 96 + 255) / 256, 256, 0, stream>>>(T0, pcw, pcb, T1);
  // LN1 -> H (bf16)
  ln_k<<<MT / 4, 256, 0, stream>>>(T1, ln1w, ln1b, H);
  // qkv: QKV = H @ qkvw^T (no bias)          [25088 x 1152] bf16
  gemm_k<2><<<196 * 9, 256, 0, stream>>>(H, wb_qkv, nullptr, nullptr, QKV,
                                          MT, 1152, 384, 384, 384, 9, 0);
  // fused attention (rpe in-kernel) -> AO (bf16)
  attn_k<<<1536, 256, 0, stream>>>(QKV, rpet, AO);
  // proj + residual(T1) -> T2 (f32)
  gemm_k<3><<<196 * 3, 256, 0, stream>>>(AO, wb_proj, projb, T1, T2,
                                          MT, 384, 384, 384, 384, 3, 0);
  // LN2 -> H2 (bf16)
  ln_k<<<MT / 4, 256, 0, stream>>>(T2, ln2w, ln2b, H2);
  // mlp fc1: MLP1 = relu6(H2 @ m1w^T + b)    [25088 x 1536] bf16
  gemm_k<0><<<196 * 12, 256, 0, stream>>>(H2, wb_m1, m1b, nullptr, MLP1,
                                           MT, 1536, 384, 384, 384, 12, 0);
  // mlp fc2 + residual(T2) -> T3 (f32)
  gemm_k<3><<<196 * 3, 256, 0, stream>>>(MLP1, wb_m2, m2b, T2, T3,
                                          MT, 384, 1536, 1536, 1536, 3, 0);
  // BN1 (per position) -> T3nb (bf16)
  bn1_partial_k<<<196 * 8, 256, 0, stream>>>(T3, bnP);
  bn1_finish_k<<<1, 256, 0, stream>>>(bnP, bn1w, bn1b, bnS, bnSh);
  bn1_apply_k<<<(MT * DM / 4 + 255) / 256, 256, 0, stream>>>(T3, bnS, bnSh, T3nb);
  // lin head: y = T3nb(128 x 75264) @ linw^T, split-K 49 x 1536 (W f32 direct)
  gemm_k<4><<<3 * 49, 256, 0, stream>>>(T3nb, linw, nullptr, nullptr, PART,
                                         128, 384, 1536, 75264, 75264, 3, 1536);
  lin_reduce_k<<<192, 256, 0, stream>>>(PART, linb, y);
  // BN2 (per feature over batch), in place on d_out
  bn2_k<<<384, 64, 0, stream>>>(y, bn2w, bn2b);
}